// Round 2
// baseline (662.942 us; speedup 1.0000x reference)
//
#include <hip/hip_runtime.h>
#include <hip/hip_bf16.h>

// All reference dtypes are float32 -> inputs are const float*, output float*.

// ---------- generic tiled GEMM: C = act(A @ B + bias), fp32 ----------
// A: [M,K] fp32, B: [K,N] fp32, bias: [N] fp32, C: fp32 row pitch N,
// output row index = m*row_mul + row_add (lets the act GEMM scatter into obj rows g*16+8).
template<int RELU>
__global__ __launch_bounds__(256)
void gemm_bias(const float* __restrict__ A, const float* __restrict__ B,
               const float* __restrict__ bias, float* __restrict__ C,
               int M, int N, int K, int row_mul, int row_add)
{
    __shared__ float As[16][68];   // As[k][m] (transposed store)
    __shared__ float Bs[16][68];   // Bs[k][n]
    const int t  = threadIdx.x;
    const int bm = blockIdx.y * 64;
    const int bn = blockIdx.x * 64;
    const int tm = t >> 4, tn = t & 15;          // 16x16 threads, 4x4 microtile
    const int arow = t >> 2, akq = (t & 3) * 4;  // A tile: 64 rows x 16 k
    const int brow = t >> 4, bnq = (t & 15) * 4; // B tile: 16 k x 64 n

    float acc[4][4];
#pragma unroll
    for (int i = 0; i < 4; i++)
#pragma unroll
        for (int j = 0; j < 4; j++) acc[i][j] = 0.f;

    for (int k0 = 0; k0 < K; k0 += 16) {
        const float4 av = *(const float4*)(A + (size_t)(bm + arow) * K + k0 + akq);
        float4 bv4;
        {
            const int nb = bn + bnq;
            const float* bp = B + (size_t)(k0 + brow) * N + nb;
            if (nb + 3 < N) {
                bv4 = *(const float4*)bp;
            } else {
                bv4.x = (nb + 0 < N) ? bp[0] : 0.f;
                bv4.y = (nb + 1 < N) ? bp[1] : 0.f;
                bv4.z = (nb + 2 < N) ? bp[2] : 0.f;
                bv4.w = (nb + 3 < N) ? bp[3] : 0.f;
            }
        }
        As[akq + 0][arow] = av.x;
        As[akq + 1][arow] = av.y;
        As[akq + 2][arow] = av.z;
        As[akq + 3][arow] = av.w;
        *(float4*)&Bs[brow][bnq] = bv4;
        __syncthreads();
#pragma unroll
        for (int kk = 0; kk < 16; kk++) {
            const float4 a4 = *(const float4*)&As[kk][tm * 4];
            const float4 b4 = *(const float4*)&Bs[kk][tn * 4];
            acc[0][0] = fmaf(a4.x, b4.x, acc[0][0]);
            acc[0][1] = fmaf(a4.x, b4.y, acc[0][1]);
            acc[0][2] = fmaf(a4.x, b4.z, acc[0][2]);
            acc[0][3] = fmaf(a4.x, b4.w, acc[0][3]);
            acc[1][0] = fmaf(a4.y, b4.x, acc[1][0]);
            acc[1][1] = fmaf(a4.y, b4.y, acc[1][1]);
            acc[1][2] = fmaf(a4.y, b4.z, acc[1][2]);
            acc[1][3] = fmaf(a4.y, b4.w, acc[1][3]);
            acc[2][0] = fmaf(a4.z, b4.x, acc[2][0]);
            acc[2][1] = fmaf(a4.z, b4.y, acc[2][1]);
            acc[2][2] = fmaf(a4.z, b4.z, acc[2][2]);
            acc[2][3] = fmaf(a4.z, b4.w, acc[2][3]);
            acc[3][0] = fmaf(a4.w, b4.x, acc[3][0]);
            acc[3][1] = fmaf(a4.w, b4.y, acc[3][1]);
            acc[3][2] = fmaf(a4.w, b4.z, acc[3][2]);
            acc[3][3] = fmaf(a4.w, b4.w, acc[3][3]);
        }
        __syncthreads();
    }

    float bv[4];
#pragma unroll
    for (int j = 0; j < 4; j++) {
        const int n = bn + tn * 4 + j;
        bv[j] = (n < N) ? bias[n] : 0.f;
    }
#pragma unroll
    for (int i = 0; i < 4; i++) {
        const int m = bm + tm * 4 + i;
        const size_t rbase = ((size_t)m * row_mul + row_add) * (size_t)N;
#pragma unroll
        for (int j = 0; j < 4; j++) {
            const int n = bn + tn * 4 + j;
            if (n < N) {
                float v = acc[i][j] + bv[j];
                if (RELU) v = fmaxf(v, 0.f);
                C[rbase + n] = v;
            }
        }
    }
}

// ---------- per-graph kernel: one block per graph (2048 blocks, 256 threads) ----------
// Algebraic collapse (mean over D of both GCN branches):
//   gmean[n] = 0.5*(b2[n]+b4[n]) + (1/32)*( sum_k zc1[k]*W2[k,n] + sum_k zc4[k]*W4[k,n] )
//   zc1[k] = sum_j colsum(adj)[j]*x1[j,k],  zc4[k] = sum_j colsum(adjh3)[j]*y2[j,k]
#define XPAD 516

__global__ __launch_bounds__(256)
void graph_kernel(const float* __restrict__ obj,
                  const float* __restrict__ W1, const float* __restrict__ b1,
                  const float* __restrict__ W2, const float* __restrict__ b2,
                  const float* __restrict__ W3, const float* __restrict__ b3,
                  const float* __restrict__ W4, const float* __restrict__ b4,
                  float* __restrict__ cbuf)
{
    __shared__ float xs[16][XPAD];     // x tile, fp32, padded (2-way bank alias max: free)
    __shared__ float ss[16][17];       // scores -> exp(scores)
    __shared__ float adjs[16][17];     // normalized adjacency
    __shared__ float t1s[16][36];      // x@W1
    __shared__ float t3s[16][36];      // x@W3
    __shared__ float x1s[16][36];      // relu(adj@t1+b1)
    __shared__ float y2s[16][36];      // relu(adj@t3+b3)
    __shared__ float y22s[16][17];
    __shared__ float adj3s[16][17];
    __shared__ float rowa[16];         // nrm
    __shared__ float dv[16], dv3[16];
    __shared__ float cA[16], cA3[16];
    __shared__ float zc1[32], zc4[32];

    const int g = blockIdx.x;
    const int t = threadIdx.x;

    // 1. load x [16,512] fp32, coalesced float4
    {
        const float4* xg = (const float4*)(obj + (size_t)g * (16 * 512));
#pragma unroll
        for (int v = 0; v < 8; v++) {
            const int idx = t + v * 256;
            const int i = idx >> 7;        // 128 float4 per row
            const int kq = idx & 127;
            *(float4*)&xs[i][kq * 4] = xg[idx];
        }
    }
    __syncthreads();

    // 2. omean for columns n0=2t, n1=2t+1
    float o0 = 0.f, o1 = 0.f;
#pragma unroll
    for (int i = 0; i < 16; i++) {
        const float2 v = *(const float2*)&xs[i][2 * t];
        o0 += v.x; o1 += v.y;
    }
    o0 *= 0.0625f; o1 *= 0.0625f;

    const int si = t >> 4, sj = t & 15;

    // 3. s = x x^T
    {
        const float4* xi = (const float4*)&xs[si][0];
        const float4* xj = (const float4*)&xs[sj][0];
        float a = 0.f;
        for (int k = 0; k < 128; k++) {
            const float4 p = xi[k], q = xj[k];
            a = fmaf(p.x, q.x, a); a = fmaf(p.y, q.y, a);
            a = fmaf(p.z, q.z, a); a = fmaf(p.w, q.w, a);
        }
        ss[si][sj] = a;
    }
    __syncthreads();

    // 4. rowwise exp(s - max) and d = rsqrt(rowsum)
    if (t < 16) {
        float m = ss[t][0];
#pragma unroll
        for (int j = 1; j < 16; j++) m = fmaxf(m, ss[t][j]);
        float sum = 0.f;
#pragma unroll
        for (int j = 0; j < 16; j++) { const float e = expf(ss[t][j] - m); ss[t][j] = e; sum += e; }
        dv[t] = rsqrtf(sum);
    }
    __syncthreads();
    adjs[si][sj] = ss[si][sj] * dv[si] * dv[sj];
    // visibility of adjs guaranteed by syncs inside step 5's reduction

    // 5. t1 = x@W1, t3 = x@W3  [16,32]; k-split 4 ways, float4 weight loads
    {
        const int q  = t & 3;          // c-octet: c = 8q..8q+7
        const int i  = (t >> 2) & 15;  // row
        const int kh = t >> 6;         // k-quarter
        float acc1[8], acc3[8];
#pragma unroll
        for (int j = 0; j < 8; j++) { acc1[j] = 0.f; acc3[j] = 0.f; }
        const float4* xrow = (const float4*)&xs[i][0];
        for (int k4 = kh * 32; k4 < kh * 32 + 32; k4++) {
            const float4 xv = xrow[k4];
            const float xk[4] = {xv.x, xv.y, xv.z, xv.w};
#pragma unroll
            for (int dk = 0; dk < 4; dk++) {
                const int k = 4 * k4 + dk;
                const float4 w1a = *(const float4*)&W1[k * 32 + 8 * q];
                const float4 w1b = *(const float4*)&W1[k * 32 + 8 * q + 4];
                const float4 w3a = *(const float4*)&W3[k * 32 + 8 * q];
                const float4 w3b = *(const float4*)&W3[k * 32 + 8 * q + 4];
                const float xkv = xk[dk];
                acc1[0] = fmaf(xkv, w1a.x, acc1[0]);
                acc1[1] = fmaf(xkv, w1a.y, acc1[1]);
                acc1[2] = fmaf(xkv, w1a.z, acc1[2]);
                acc1[3] = fmaf(xkv, w1a.w, acc1[3]);
                acc1[4] = fmaf(xkv, w1b.x, acc1[4]);
                acc1[5] = fmaf(xkv, w1b.y, acc1[5]);
                acc1[6] = fmaf(xkv, w1b.z, acc1[6]);
                acc1[7] = fmaf(xkv, w1b.w, acc1[7]);
                acc3[0] = fmaf(xkv, w3a.x, acc3[0]);
                acc3[1] = fmaf(xkv, w3a.y, acc3[1]);
                acc3[2] = fmaf(xkv, w3a.z, acc3[2]);
                acc3[3] = fmaf(xkv, w3a.w, acc3[3]);
                acc3[4] = fmaf(xkv, w3b.x, acc3[4]);
                acc3[5] = fmaf(xkv, w3b.y, acc3[5]);
                acc3[6] = fmaf(xkv, w3b.z, acc3[6]);
                acc3[7] = fmaf(xkv, w3b.w, acc3[7]);
            }
        }
        // sequential k-split reduction (uniform control flow around syncs)
        for (int ph = 0; ph < 4; ph++) {
            if (kh == ph) {
                if (ph == 0) {
#pragma unroll
                    for (int j = 0; j < 8; j++) { t1s[i][8 * q + j] = acc1[j]; t3s[i][8 * q + j] = acc3[j]; }
                } else {
#pragma unroll
                    for (int j = 0; j < 8; j++) { t1s[i][8 * q + j] += acc1[j]; t3s[i][8 * q + j] += acc3[j]; }
                }
            }
            __syncthreads();
        }
    }

    // 6. x1 = relu(adj@t1 + b1), y2 = relu(adj@t3 + b3)
    {
        const int c = t & 31, r = t >> 5;  // r 0..7, rows r and r+8
        const float bb1 = b1[c], bb3 = b3[c];
        float a0 = bb1, a1 = bb1, a2 = bb3, a3 = bb3;
#pragma unroll
        for (int j = 0; j < 16; j++) {
            const float t1v = t1s[j][c], t3v = t3s[j][c];
            const float ar = adjs[r][j], a8 = adjs[r + 8][j];
            a0 = fmaf(ar, t1v, a0); a1 = fmaf(a8, t1v, a1);
            a2 = fmaf(ar, t3v, a2); a3 = fmaf(a8, t3v, a3);
        }
        x1s[r][c] = fmaxf(a0, 0.f); x1s[r + 8][c] = fmaxf(a1, 0.f);
        y2s[r][c] = fmaxf(a2, 0.f); y2s[r + 8][c] = fmaxf(a3, 0.f);
    }
    __syncthreads();

    // 7. y22 = y2 y2^T
    {
        const float4* ya = (const float4*)&y2s[si][0];
        const float4* yb = (const float4*)&y2s[sj][0];
        float a = 0.f;
#pragma unroll
        for (int k = 0; k < 8; k++) {
            const float4 p = ya[k], q = yb[k];
            a = fmaf(p.x, q.x, a); a = fmaf(p.y, q.y, a);
            a = fmaf(p.z, q.z, a); a = fmaf(p.w, q.w, a);
        }
        y22s[si][sj] = a;
    }
    __syncthreads();

    // 8. nrm = ||y22 row||_2
    if (t < 16) {
        float sq = 0.f;
#pragma unroll
        for (int j = 0; j < 16; j++) { const float v = y22s[t][j]; sq = fmaf(v, v, sq); }
        rowa[t] = sqrtf(sq);
    }
    __syncthreads();

    // 9. adj3 = 1 + y22/(nrm_i*nrm_j)
    adj3s[si][sj] = 1.0f + y22s[si][sj] / (rowa[si] * rowa[sj]);
    __syncthreads();

    // 10. d3 = rsqrt(rowsum(adj3))
    if (t < 16) {
        float sum = 0.f;
#pragma unroll
        for (int j = 0; j < 16; j++) sum += adj3s[t][j];
        dv3[t] = rsqrtf(sum);
    }
    __syncthreads();

    // 11. adjh3 in place
    adj3s[si][sj] *= dv3[si] * dv3[sj];
    __syncthreads();

    // column sums of adj and adjh3
    if (t < 16) {
        float s1 = 0.f, s2 = 0.f;
#pragma unroll
        for (int i = 0; i < 16; i++) { s1 += adjs[i][t]; s2 += adj3s[i][t]; }
        cA[t] = s1; cA3[t] = s2;
    }
    __syncthreads();

    // 12. zc1[k] = sum_j cA[j]*x1[j,k],  zc4[k] = sum_j cA3[j]*y2[j,k]
    if (t < 32) {
        float s1 = 0.f, s2 = 0.f;
#pragma unroll
        for (int j = 0; j < 16; j++) {
            s1 = fmaf(cA[j], x1s[j][t], s1);
            s2 = fmaf(cA3[j], y2s[j][t], s2);
        }
        zc1[t] = s1; zc4[t] = s2;
    }
    __syncthreads();

    // 13. final: columns n0=2t, n1=2t+1  ->  cbuf = relu(0.5*(omean+gmean))
    {
        const float2* W2p = (const float2*)W2;  // [32,512] -> [k*256 + t] = cols 2t,2t+1
        const float2* W4p = (const float2*)W4;
        float g0 = 0.f, g1 = 0.f;
        for (int k = 0; k < 32; k++) {
            const float z1 = zc1[k], z4 = zc4[k];
            const float2 p2 = W2p[k * 256 + t];
            const float2 p4 = W4p[k * 256 + t];
            g0 = fmaf(z1, p2.x, g0); g1 = fmaf(z1, p2.y, g1);
            g0 = fmaf(z4, p4.x, g0); g1 = fmaf(z4, p4.y, g1);
        }
        const float2 pb2 = ((const float2*)b2)[t];
        const float2 pb4 = ((const float2*)b4)[t];
        const float gm0 = 0.5f * (pb2.x + pb4.x) + g0 * (1.0f / 32.0f);
        const float gm1 = 0.5f * (pb2.y + pb4.y) + g1 * (1.0f / 32.0f);
        float2 st;
        st.x = fmaxf(0.5f * (o0 + gm0), 0.f);
        st.y = fmaxf(0.5f * (o1 + gm1), 0.f);
        *(float2*)&cbuf[(size_t)g * 512 + 2 * t] = st;
    }
}

// ---------- final mean over T=64 ----------
__global__ __launch_bounds__(256)
void reduce_mean_T(const float* __restrict__ outT, float* __restrict__ out)
{
    const int idx = blockIdx.x * 256 + threadIdx.x;
    if (idx >= 32 * 500) return;
    const int n = idx / 500, j = idx - n * 500;
    const float* p = outT + (size_t)n * 64 * 500 + j;
    float s = 0.f;
#pragma unroll 8
    for (int tt = 0; tt < 64; tt++) s += p[tt * 500];
    out[idx] = s * (1.0f / 64.0f);
}

// ---------- launcher ----------
extern "C" void kernel_launch(void* const* d_in, const int* in_sizes, int n_in,
                              void* d_out, int out_size, void* d_ws, size_t ws_size,
                              hipStream_t stream)
{
    const float* object_raw = (const float*)d_in[0];
    const float* action_raw = (const float*)d_in[1];
    const float* W_obj = (const float*)d_in[2];
    const float* b_obj = (const float*)d_in[3];
    const float* W_act = (const float*)d_in[4];
    const float* b_act = (const float*)d_in[5];
    const float* gc1_W = (const float*)d_in[6];
    const float* gc1_b = (const float*)d_in[7];
    const float* gc2_W = (const float*)d_in[8];
    const float* gc2_b = (const float*)d_in[9];
    const float* gc3_W = (const float*)d_in[10];
    const float* gc3_b = (const float*)d_in[11];
    const float* gc4_W = (const float*)d_in[12];
    const float* gc4_b = (const float*)d_in[13];
    const float* fc1_W = (const float*)d_in[14];
    const float* fc1_b = (const float*)d_in[15];
    const float* clf_W = (const float*)d_in[16];
    const float* clf_b = (const float*)d_in[17];

    // workspace layout (fp32), peak 68MB:
    //   obj  [0, 64MB)           -- dead after graph_kernel
    //   cbuf [64MB, 68MB)
    //   c2   [0, 8MB)   (aliases dead obj)
    //   outT [8MB, 12MB)
    float* obj  = (float*)d_ws;
    float* cbuf = obj + (size_t)32768 * 512;
    float* c2   = (float*)d_ws;
    float* outT = c2 + (size_t)2048 * 1024;

    // 1. obj = relu(object_raw @ W_obj + b_obj)   [32768,512]
    gemm_bias<1><<<dim3(8, 512), 256, 0, stream>>>(
        object_raw, W_obj, b_obj, obj, 32768, 512, 512, 1, 0);
    // 2. act = relu(action_raw @ W_act + b_act) scattered into obj rows g*16+8
    gemm_bias<1><<<dim3(8, 32), 256, 0, stream>>>(
        action_raw, W_act, b_act, obj, 2048, 512, 512, 16, 8);
    // 3. per-graph GCN -> cbuf = relu(feat)   [2048,512]
    graph_kernel<<<dim3(2048), 256, 0, stream>>>(
        obj, gc1_W, gc1_b, gc2_W, gc2_b, gc3_W, gc3_b, gc4_W, gc4_b, cbuf);
    // 4. c2 = relu(cbuf @ fc1_W + fc1_b)   [2048,1024]  (c2 aliases dead obj region)
    gemm_bias<1><<<dim3(16, 32), 256, 0, stream>>>(
        cbuf, fc1_W, fc1_b, c2, 2048, 1024, 512, 1, 0);
    // 5. outT = c2 @ clf_W + clf_b   [2048,500]
    gemm_bias<0><<<dim3(8, 32), 256, 0, stream>>>(
        c2, clf_W, clf_b, outT, 2048, 500, 1024, 1, 0);
    // 6. mean over T -> fp32 out [32,500]
    reduce_mean_T<<<dim3(63), 256, 0, stream>>>(outT, (float*)d_out);
}

// Round 3
// 383.456 us; speedup vs baseline: 1.7289x; 1.7289x over previous
//
#include <hip/hip_runtime.h>
#include <hip/hip_bf16.h>

using ushort_t = unsigned short;
using f32x4  = __attribute__((ext_vector_type(4))) float;
using short8 = __attribute__((ext_vector_type(8))) short;

// ---------- bf16 helpers ----------
__device__ __forceinline__ float bflo(unsigned p) {
    union { unsigned u; float f; } x; x.u = p << 16; return x.f;
}
__device__ __forceinline__ float bfhi(unsigned p) {
    union { unsigned u; float f; } x; x.u = p & 0xffff0000u; return x.f;
}
__device__ __forceinline__ ushort_t f2bf(float f) {
    __hip_bfloat16 h = __float2bfloat16(f);   // RTNE
    return *(ushort_t*)&h;
}

// ---------- fp32 -> bf16 elementwise convert (8 els/thread) ----------
__global__ __launch_bounds__(256)
void cvt_bf16x8(const float* __restrict__ a, ushort_t* __restrict__ o, int n8)
{
    const int i = blockIdx.x * 256 + threadIdx.x;
    if (i >= n8) return;
    const float4 x = ((const float4*)a)[2 * i];
    const float4 y = ((const float4*)a)[2 * i + 1];
    ushort_t r[8] = { f2bf(x.x), f2bf(x.y), f2bf(x.z), f2bf(x.w),
                      f2bf(y.x), f2bf(y.y), f2bf(y.z), f2bf(y.w) };
    ((uint4*)o)[i] = *(uint4*)r;
}

// ---------- fp32 B[K,N] -> bf16 Bt[Npad,K] transpose+convert ----------
__global__ __launch_bounds__(256)
void transpose_cvt(const float* __restrict__ B, ushort_t* __restrict__ Bt,
                   int K, int N, int Npad)
{
    __shared__ float tile[32][33];
    const int k0 = blockIdx.y * 32, n0 = blockIdx.x * 32;
    const int tx = threadIdx.x, ty = threadIdx.y;   // (32, 8)
#pragma unroll
    for (int r = 0; r < 4; r++) {
        const int k = k0 + ty + r * 8, n = n0 + tx;
        tile[ty + r * 8][tx] = (k < K && n < N) ? B[(size_t)k * N + n] : 0.f;
    }
    __syncthreads();
#pragma unroll
    for (int r = 0; r < 4; r++) {
        const int n = n0 + ty + r * 8, k = k0 + tx;
        if (n < Npad && k < K) Bt[(size_t)n * K + k] = f2bf(tile[tx][ty + r * 8]);
    }
}

// ---------- MFMA GEMM: C = act(A @ B + bias) ----------
// A: bf16 [M,K] row-major.  Bt: bf16 [N,K] (= B^T).  bias: fp32 (read n<Nb else 0).
// C: OT (ushort bf16 or float), pitch N, row index m*row_mul+row_add.
// Tile 128x128, BK=32, 4 waves: wave w -> 64x64 quadrant, 4x4 of 16x16x32 MFMA.
// LDS row stride 56 bf16 = 112 B (16B-aligned; frag-read start banks period-8 -> 2-way, free).
__device__ __forceinline__ void store_out(ushort_t* C, size_t idx, float v) { C[idx] = f2bf(v); }
__device__ __forceinline__ void store_out(float* C, size_t idx, float v)    { C[idx] = v; }

template<int RELU, typename OT>
__global__ __launch_bounds__(256)
void gemm_mfma(const ushort_t* __restrict__ A, const ushort_t* __restrict__ Bt,
               const float* __restrict__ bias, OT* __restrict__ C,
               int M, int N, int K, int Nb, int row_mul, int row_add)
{
    __shared__ ushort_t As[128 * 56];
    __shared__ ushort_t Bs[128 * 56];
    const int t = threadIdx.x;
    const int lane = t & 63, w = t >> 6;
    const int bm = blockIdx.y * 128, bn = blockIdx.x * 128;
    const int mb = (w & 1) * 64, nb = (w >> 1) * 64;

    // staging: thread handles chunk ids t and t+256; id -> row=id>>2, kchunk=id&3 (8 bf16)
    const int r0 = t >> 2, kc0 = t & 3;
    const ushort_t* Ag = A  + (size_t)(bm + r0) * K + kc0 * 8;
    const ushort_t* Bg = Bt + (size_t)(bn + r0) * K + kc0 * 8;
    const size_t rowskip = (size_t)64 * K;

    f32x4 acc[16];
#pragma unroll
    for (int i = 0; i < 16; i++) acc[i] = (f32x4){0.f, 0.f, 0.f, 0.f};

    const int fr = lane & 15, fq = lane >> 4;

    for (int k0 = 0; k0 < K; k0 += 32) {
        __syncthreads();
        const uint4 a0 = *(const uint4*)(Ag + k0);
        const uint4 a1 = *(const uint4*)(Ag + rowskip + k0);
        const uint4 b0 = *(const uint4*)(Bg + k0);
        const uint4 b1 = *(const uint4*)(Bg + rowskip + k0);
        *(uint4*)&As[(r0)      * 56 + kc0 * 8] = a0;
        *(uint4*)&As[(r0 + 64) * 56 + kc0 * 8] = a1;
        *(uint4*)&Bs[(r0)      * 56 + kc0 * 8] = b0;
        *(uint4*)&Bs[(r0 + 64) * 56 + kc0 * 8] = b1;
        __syncthreads();

        short8 af[4], bf[4];
#pragma unroll
        for (int i = 0; i < 4; i++)
            af[i] = *(const short8*)&As[(mb + i * 16 + fr) * 56 + fq * 8];
#pragma unroll
        for (int j = 0; j < 4; j++)
            bf[j] = *(const short8*)&Bs[(nb + j * 16 + fr) * 56 + fq * 8];
#pragma unroll
        for (int i = 0; i < 4; i++)
#pragma unroll
            for (int j = 0; j < 4; j++)
                acc[i * 4 + j] = __builtin_amdgcn_mfma_f32_16x16x32_bf16(
                    af[i], bf[j], acc[i * 4 + j], 0, 0, 0);
    }

    // epilogue: row = (lane>>4)*4 + reg, col = lane&15  (m89-verified C/D layout)
#pragma unroll
    for (int j = 0; j < 4; j++) {
        const int n = bn + nb + j * 16 + fr;
        const float bv = (n < Nb) ? bias[n] : 0.f;
#pragma unroll
        for (int i = 0; i < 4; i++) {
            const f32x4 a = acc[i * 4 + j];
#pragma unroll
            for (int r = 0; r < 4; r++) {
                const int m = bm + mb + i * 16 + fq * 4 + r;
                float v = a[r] + bv;
                if (RELU) v = fmaxf(v, 0.f);
                store_out(C, ((size_t)m * row_mul + row_add) * (size_t)N + n, v);
            }
        }
    }
}

// ---------- per-graph kernel (bf16 in / bf16 out, fp32 internals) ----------
#define XPAD 516

__global__ __launch_bounds__(256)
void graph_kernel(const ushort_t* __restrict__ obj,
                  const float* __restrict__ W1, const float* __restrict__ b1,
                  const float* __restrict__ W2, const float* __restrict__ b2,
                  const float* __restrict__ W3, const float* __restrict__ b3,
                  const float* __restrict__ W4, const float* __restrict__ b4,
                  ushort_t* __restrict__ cbuf)
{
    __shared__ float xs[16][XPAD];
    __shared__ float ss[16][17];
    __shared__ float adjs[16][17];
    __shared__ float t1s[16][36];
    __shared__ float t3s[16][36];
    __shared__ float x1s[16][36];
    __shared__ float y2s[16][36];
    __shared__ float y22s[16][17];
    __shared__ float adj3s[16][17];
    __shared__ float rowa[16];
    __shared__ float dv[16], dv3[16];
    __shared__ float cA[16], cA3[16];
    __shared__ float zc1[32], zc4[32];

    const int g = blockIdx.x;
    const int t = threadIdx.x;

    // 1. load x [16,512] bf16 -> fp32 LDS
    {
        const uint4* xg = (const uint4*)(obj + (size_t)g * (16 * 512));
#pragma unroll
        for (int v = 0; v < 4; v++) {
            const int idx = t + v * 256;     // 1024 uint4 total
            const int i = idx >> 6;          // 64 uint4 per row
            const int kq = idx & 63;
            const uint4 q = xg[idx];
            float* d = &xs[i][kq * 8];
            d[0] = bflo(q.x); d[1] = bfhi(q.x); d[2] = bflo(q.y); d[3] = bfhi(q.y);
            d[4] = bflo(q.z); d[5] = bfhi(q.z); d[6] = bflo(q.w); d[7] = bfhi(q.w);
        }
    }
    __syncthreads();

    // 2. omean for columns 2t, 2t+1
    float o0 = 0.f, o1 = 0.f;
#pragma unroll
    for (int i = 0; i < 16; i++) {
        const float2 v = *(const float2*)&xs[i][2 * t];
        o0 += v.x; o1 += v.y;
    }
    o0 *= 0.0625f; o1 *= 0.0625f;

    const int si = t >> 4, sj = t & 15;

    // 3. s = x x^T
    {
        const float4* xi = (const float4*)&xs[si][0];
        const float4* xj = (const float4*)&xs[sj][0];
        float a = 0.f;
        for (int k = 0; k < 128; k++) {
            const float4 p = xi[k], q = xj[k];
            a = fmaf(p.x, q.x, a); a = fmaf(p.y, q.y, a);
            a = fmaf(p.z, q.z, a); a = fmaf(p.w, q.w, a);
        }
        ss[si][sj] = a;
    }
    __syncthreads();

    // 4. rowwise exp(s - max), d = rsqrt(rowsum)
    if (t < 16) {
        float m = ss[t][0];
#pragma unroll
        for (int j = 1; j < 16; j++) m = fmaxf(m, ss[t][j]);
        float sum = 0.f;
#pragma unroll
        for (int j = 0; j < 16; j++) { const float e = expf(ss[t][j] - m); ss[t][j] = e; sum += e; }
        dv[t] = rsqrtf(sum);
    }
    __syncthreads();
    adjs[si][sj] = ss[si][sj] * dv[si] * dv[sj];

    // 5. t1 = x@W1, t3 = x@W3  [16,32]; k-split 4 ways
    {
        const int q  = t & 3;
        const int i  = (t >> 2) & 15;
        const int kh = t >> 6;
        float acc1[8], acc3[8];
#pragma unroll
        for (int j = 0; j < 8; j++) { acc1[j] = 0.f; acc3[j] = 0.f; }
        const float4* xrow = (const float4*)&xs[i][0];
        for (int k4 = kh * 32; k4 < kh * 32 + 32; k4++) {
            const float4 xv = xrow[k4];
            const float xk[4] = {xv.x, xv.y, xv.z, xv.w};
#pragma unroll
            for (int dk = 0; dk < 4; dk++) {
                const int k = 4 * k4 + dk;
                const float4 w1a = *(const float4*)&W1[k * 32 + 8 * q];
                const float4 w1b = *(const float4*)&W1[k * 32 + 8 * q + 4];
                const float4 w3a = *(const float4*)&W3[k * 32 + 8 * q];
                const float4 w3b = *(const float4*)&W3[k * 32 + 8 * q + 4];
                const float xkv = xk[dk];
                acc1[0] = fmaf(xkv, w1a.x, acc1[0]);
                acc1[1] = fmaf(xkv, w1a.y, acc1[1]);
                acc1[2] = fmaf(xkv, w1a.z, acc1[2]);
                acc1[3] = fmaf(xkv, w1a.w, acc1[3]);
                acc1[4] = fmaf(xkv, w1b.x, acc1[4]);
                acc1[5] = fmaf(xkv, w1b.y, acc1[5]);
                acc1[6] = fmaf(xkv, w1b.z, acc1[6]);
                acc1[7] = fmaf(xkv, w1b.w, acc1[7]);
                acc3[0] = fmaf(xkv, w3a.x, acc3[0]);
                acc3[1] = fmaf(xkv, w3a.y, acc3[1]);
                acc3[2] = fmaf(xkv, w3a.z, acc3[2]);
                acc3[3] = fmaf(xkv, w3a.w, acc3[3]);
                acc3[4] = fmaf(xkv, w3b.x, acc3[4]);
                acc3[5] = fmaf(xkv, w3b.y, acc3[5]);
                acc3[6] = fmaf(xkv, w3b.z, acc3[6]);
                acc3[7] = fmaf(xkv, w3b.w, acc3[7]);
            }
        }
        for (int ph = 0; ph < 4; ph++) {
            if (kh == ph) {
                if (ph == 0) {
#pragma unroll
                    for (int j = 0; j < 8; j++) { t1s[i][8 * q + j] = acc1[j]; t3s[i][8 * q + j] = acc3[j]; }
                } else {
#pragma unroll
                    for (int j = 0; j < 8; j++) { t1s[i][8 * q + j] += acc1[j]; t3s[i][8 * q + j] += acc3[j]; }
                }
            }
            __syncthreads();
        }
    }

    // 6. x1 = relu(adj@t1+b1), y2 = relu(adj@t3+b3)
    {
        const int c = t & 31, r = t >> 5;
        const float bb1 = b1[c], bb3 = b3[c];
        float a0 = bb1, a1 = bb1, a2 = bb3, a3 = bb3;
#pragma unroll
        for (int j = 0; j < 16; j++) {
            const float t1v = t1s[j][c], t3v = t3s[j][c];
            const float ar = adjs[r][j], a8 = adjs[r + 8][j];
            a0 = fmaf(ar, t1v, a0); a1 = fmaf(a8, t1v, a1);
            a2 = fmaf(ar, t3v, a2); a3 = fmaf(a8, t3v, a3);
        }
        x1s[r][c] = fmaxf(a0, 0.f); x1s[r + 8][c] = fmaxf(a1, 0.f);
        y2s[r][c] = fmaxf(a2, 0.f); y2s[r + 8][c] = fmaxf(a3, 0.f);
    }
    __syncthreads();

    // 7. y22 = y2 y2^T
    {
        const float4* ya = (const float4*)&y2s[si][0];
        const float4* yb = (const float4*)&y2s[sj][0];
        float a = 0.f;
#pragma unroll
        for (int k = 0; k < 8; k++) {
            const float4 p = ya[k], q = yb[k];
            a = fmaf(p.x, q.x, a); a = fmaf(p.y, q.y, a);
            a = fmaf(p.z, q.z, a); a = fmaf(p.w, q.w, a);
        }
        y22s[si][sj] = a;
    }
    __syncthreads();

    // 8. nrm
    if (t < 16) {
        float sq = 0.f;
#pragma unroll
        for (int j = 0; j < 16; j++) { const float v = y22s[t][j]; sq = fmaf(v, v, sq); }
        rowa[t] = sqrtf(sq);
    }
    __syncthreads();

    // 9. adj3
    adj3s[si][sj] = 1.0f + y22s[si][sj] / (rowa[si] * rowa[sj]);
    __syncthreads();

    // 10. d3
    if (t < 16) {
        float sum = 0.f;
#pragma unroll
        for (int j = 0; j < 16; j++) sum += adj3s[t][j];
        dv3[t] = rsqrtf(sum);
    }
    __syncthreads();

    // 11. adjh3 in place
    adj3s[si][sj] *= dv3[si] * dv3[sj];
    __syncthreads();

    // column sums
    if (t < 16) {
        float s1 = 0.f, s2 = 0.f;
#pragma unroll
        for (int i = 0; i < 16; i++) { s1 += adjs[i][t]; s2 += adj3s[i][t]; }
        cA[t] = s1; cA3[t] = s2;
    }
    __syncthreads();

    // 12. zc
    if (t < 32) {
        float s1 = 0.f, s2 = 0.f;
#pragma unroll
        for (int j = 0; j < 16; j++) {
            s1 = fmaf(cA[j], x1s[j][t], s1);
            s2 = fmaf(cA3[j], y2s[j][t], s2);
        }
        zc1[t] = s1; zc4[t] = s2;
    }
    __syncthreads();

    // 13. cbuf = relu(0.5*(omean+gmean)) -> bf16
    {
        const float2* W2p = (const float2*)W2;
        const float2* W4p = (const float2*)W4;
        float g0 = 0.f, g1 = 0.f;
        for (int k = 0; k < 32; k++) {
            const float z1 = zc1[k], z4 = zc4[k];
            const float2 p2 = W2p[k * 256 + t];
            const float2 p4 = W4p[k * 256 + t];
            g0 = fmaf(z1, p2.x, g0); g1 = fmaf(z1, p2.y, g1);
            g0 = fmaf(z4, p4.x, g0); g1 = fmaf(z4, p4.y, g1);
        }
        const float2 pb2 = ((const float2*)b2)[t];
        const float2 pb4 = ((const float2*)b4)[t];
        const float gm0 = 0.5f * (pb2.x + pb4.x) + g0 * (1.0f / 32.0f);
        const float gm1 = 0.5f * (pb2.y + pb4.y) + g1 * (1.0f / 32.0f);
        const float s0 = fmaxf(0.5f * (o0 + gm0), 0.f);
        const float s1 = fmaxf(0.5f * (o1 + gm1), 0.f);
        const unsigned pk = (unsigned)f2bf(s0) | ((unsigned)f2bf(s1) << 16);
        ((unsigned*)cbuf)[(size_t)g * 256 + t] = pk;
    }
}

// ---------- final mean over T=64 (outT pitch 512, first 500 valid) ----------
__global__ __launch_bounds__(256)
void reduce_mean_T(const float* __restrict__ outT, float* __restrict__ out)
{
    const int idx = blockIdx.x * 256 + threadIdx.x;
    if (idx >= 32 * 500) return;
    const int n = idx / 500, j = idx - n * 500;
    const float* p = outT + (size_t)n * 64 * 512 + j;
    float s = 0.f;
#pragma unroll 8
    for (int tt = 0; tt < 64; tt++) s += p[tt * 512];
    out[idx] = s * (1.0f / 64.0f);
}

// ---------- launcher ----------
extern "C" void kernel_launch(void* const* d_in, const int* in_sizes, int n_in,
                              void* d_out, int out_size, void* d_ws, size_t ws_size,
                              hipStream_t stream)
{
    const float* object_raw = (const float*)d_in[0];
    const float* action_raw = (const float*)d_in[1];
    const float* W_obj = (const float*)d_in[2];
    const float* b_obj = (const float*)d_in[3];
    const float* W_act = (const float*)d_in[4];
    const float* b_act = (const float*)d_in[5];
    const float* gc1_W = (const float*)d_in[6];
    const float* gc1_b = (const float*)d_in[7];
    const float* gc2_W = (const float*)d_in[8];
    const float* gc2_b = (const float*)d_in[9];
    const float* gc3_W = (const float*)d_in[10];
    const float* gc3_b = (const float*)d_in[11];
    const float* gc4_W = (const float*)d_in[12];
    const float* gc4_b = (const float*)d_in[13];
    const float* fc1_W = (const float*)d_in[14];
    const float* fc1_b = (const float*)d_in[15];
    const float* clf_W = (const float*)d_in[16];
    const float* clf_b = (const float*)d_in[17];

    // ws layout (bytes), peak 67MB (round-2-proven 68MB budget):
    //  [0,32M):  objA (bf16, dead after obj GEMM) -> then actA@0(2M), cbuf@2M(2M), c2@4M(4M), outT@8M(4M fp32)
    //  [32M,64M): obj_bf (bf16)
    //  [64M,67M): WobjT 512K | WactT 512K | fc1T 1M | clfT 1M
    char* ws = (char*)d_ws;
    const size_t MB = 1024 * 1024;
    ushort_t* objA   = (ushort_t*)(ws);
    ushort_t* actA   = (ushort_t*)(ws);            // reuses objA region after obj GEMM
    ushort_t* cbuf   = (ushort_t*)(ws + 2 * MB);
    ushort_t* c2     = (ushort_t*)(ws + 4 * MB);
    float*    outT   = (float*)   (ws + 8 * MB);
    ushort_t* obj_bf = (ushort_t*)(ws + 32 * MB);
    ushort_t* WobjT  = (ushort_t*)(ws + 64 * MB);
    ushort_t* WactT  = (ushort_t*)(ws + 64 * MB + 512 * 1024);
    ushort_t* fc1T   = (ushort_t*)(ws + 65 * MB);
    ushort_t* clfT   = (ushort_t*)(ws + 66 * MB);

    // weight transposes+converts
    transpose_cvt<<<dim3(16, 16), dim3(32, 8), 0, stream>>>(W_obj, WobjT, 512, 512, 512);
    transpose_cvt<<<dim3(16, 16), dim3(32, 8), 0, stream>>>(W_act, WactT, 512, 512, 512);
    transpose_cvt<<<dim3(32, 16), dim3(32, 8), 0, stream>>>(fc1_W, fc1T, 512, 1024, 1024);
    transpose_cvt<<<dim3(16, 32), dim3(32, 8), 0, stream>>>(clf_W, clfT, 1024, 500, 512);

    // obj path
    cvt_bf16x8<<<dim3(8192), 256, 0, stream>>>(object_raw, objA, 32768 * 512 / 8);
    gemm_mfma<1, ushort_t><<<dim3(4, 256), 256, 0, stream>>>(
        objA, WobjT, b_obj, obj_bf, 32768, 512, 512, 512, 1, 0);

    // act path (objA region now dead -> actA at offset 0)
    cvt_bf16x8<<<dim3(512), 256, 0, stream>>>(action_raw, actA, 2048 * 512 / 8);
    gemm_mfma<1, ushort_t><<<dim3(4, 16), 256, 0, stream>>>(
        actA, WactT, b_act, obj_bf, 2048, 512, 512, 512, 16, 8);

    // graph stage
    graph_kernel<<<dim3(2048), 256, 0, stream>>>(
        obj_bf, gc1_W, gc1_b, gc2_W, gc2_b, gc3_W, gc3_b, gc4_W, gc4_b, cbuf);

    // fc1 + clf
    gemm_mfma<1, ushort_t><<<dim3(8, 16), 256, 0, stream>>>(
        cbuf, fc1T, fc1_b, c2, 2048, 1024, 512, 1024, 1, 0);
    gemm_mfma<0, float><<<dim3(4, 16), 256, 0, stream>>>(
        c2, clfT, clf_b, outT, 2048, 512, 1024, 500, 1, 0);

    // mean over T
    reduce_mean_T<<<dim3(63), 256, 0, stream>>>(outT, (float*)d_out);
}

// Round 4
// 286.624 us; speedup vs baseline: 2.3129x; 1.3378x over previous
//
#include <hip/hip_runtime.h>
#include <hip/hip_bf16.h>

using ushort_t = unsigned short;
using f32x4  = __attribute__((ext_vector_type(4))) float;
using short8 = __attribute__((ext_vector_type(8))) short;

// ---------- bf16 helpers ----------
__device__ __forceinline__ float bflo(unsigned p) {
    union { unsigned u; float f; } x; x.u = p << 16; return x.f;
}
__device__ __forceinline__ float bfhi(unsigned p) {
    union { unsigned u; float f; } x; x.u = p & 0xffff0000u; return x.f;
}
__device__ __forceinline__ ushort_t f2bf(float f) {
    __hip_bfloat16 h = __float2bfloat16(f);   // RTNE
    return *(ushort_t*)&h;
}

// ---------- fp32 -> bf16 elementwise convert (8 els/thread) ----------
__global__ __launch_bounds__(256)
void cvt_bf16x8(const float* __restrict__ a, ushort_t* __restrict__ o, int n8)
{
    const int i = blockIdx.x * 256 + threadIdx.x;
    if (i >= n8) return;
    const float4 x = ((const float4*)a)[2 * i];
    const float4 y = ((const float4*)a)[2 * i + 1];
    ushort_t r[8] = { f2bf(x.x), f2bf(x.y), f2bf(x.z), f2bf(x.w),
                      f2bf(y.x), f2bf(y.y), f2bf(y.z), f2bf(y.w) };
    ((uint4*)o)[i] = *(uint4*)r;
}

// ---------- fp32 B[K,N] -> bf16 Bt[Npad,K] transpose+convert ----------
__global__ __launch_bounds__(256)
void transpose_cvt(const float* __restrict__ B, ushort_t* __restrict__ Bt,
                   int K, int N, int Npad)
{
    __shared__ float tile[32][33];
    const int k0 = blockIdx.y * 32, n0 = blockIdx.x * 32;
    const int tx = threadIdx.x, ty = threadIdx.y;   // (32, 8)
#pragma unroll
    for (int r = 0; r < 4; r++) {
        const int k = k0 + ty + r * 8, n = n0 + tx;
        tile[ty + r * 8][tx] = (k < K && n < N) ? B[(size_t)k * N + n] : 0.f;
    }
    __syncthreads();
#pragma unroll
    for (int r = 0; r < 4; r++) {
        const int n = n0 + ty + r * 8, k = k0 + tx;
        if (n < Npad && k < K) Bt[(size_t)n * K + k] = f2bf(tile[tx][ty + r * 8]);
    }
}

// ---------- MFMA GEMM (unchanged from round 3) ----------
__device__ __forceinline__ void store_out(ushort_t* C, size_t idx, float v) { C[idx] = f2bf(v); }
__device__ __forceinline__ void store_out(float* C, size_t idx, float v)    { C[idx] = v; }

template<int RELU, typename OT>
__global__ __launch_bounds__(256)
void gemm_mfma(const ushort_t* __restrict__ A, const ushort_t* __restrict__ Bt,
               const float* __restrict__ bias, OT* __restrict__ C,
               int M, int N, int K, int Nb, int row_mul, int row_add)
{
    __shared__ ushort_t As[128 * 56];
    __shared__ ushort_t Bs[128 * 56];
    const int t = threadIdx.x;
    const int lane = t & 63, w = t >> 6;
    const int bm = blockIdx.y * 128, bn = blockIdx.x * 128;
    const int mb = (w & 1) * 64, nb = (w >> 1) * 64;

    const int r0 = t >> 2, kc0 = t & 3;
    const ushort_t* Ag = A  + (size_t)(bm + r0) * K + kc0 * 8;
    const ushort_t* Bg = Bt + (size_t)(bn + r0) * K + kc0 * 8;
    const size_t rowskip = (size_t)64 * K;

    f32x4 acc[16];
#pragma unroll
    for (int i = 0; i < 16; i++) acc[i] = (f32x4){0.f, 0.f, 0.f, 0.f};

    const int fr = lane & 15, fq = lane >> 4;

    for (int k0 = 0; k0 < K; k0 += 32) {
        __syncthreads();
        const uint4 a0 = *(const uint4*)(Ag + k0);
        const uint4 a1 = *(const uint4*)(Ag + rowskip + k0);
        const uint4 b0 = *(const uint4*)(Bg + k0);
        const uint4 b1 = *(const uint4*)(Bg + rowskip + k0);
        *(uint4*)&As[(r0)      * 56 + kc0 * 8] = a0;
        *(uint4*)&As[(r0 + 64) * 56 + kc0 * 8] = a1;
        *(uint4*)&Bs[(r0)      * 56 + kc0 * 8] = b0;
        *(uint4*)&Bs[(r0 + 64) * 56 + kc0 * 8] = b1;
        __syncthreads();

        short8 af[4], bf[4];
#pragma unroll
        for (int i = 0; i < 4; i++)
            af[i] = *(const short8*)&As[(mb + i * 16 + fr) * 56 + fq * 8];
#pragma unroll
        for (int j = 0; j < 4; j++)
            bf[j] = *(const short8*)&Bs[(nb + j * 16 + fr) * 56 + fq * 8];
#pragma unroll
        for (int i = 0; i < 4; i++)
#pragma unroll
            for (int j = 0; j < 4; j++)
                acc[i * 4 + j] = __builtin_amdgcn_mfma_f32_16x16x32_bf16(
                    af[i], bf[j], acc[i * 4 + j], 0, 0, 0);
    }

#pragma unroll
    for (int j = 0; j < 4; j++) {
        const int n = bn + nb + j * 16 + fr;
        const float bv = (n < Nb) ? bias[n] : 0.f;
#pragma unroll
        for (int i = 0; i < 4; i++) {
            const f32x4 a = acc[i * 4 + j];
#pragma unroll
            for (int r = 0; r < 4; r++) {
                const int m = bm + mb + i * 16 + fq * 4 + r;
                float v = a[r] + bv;
                if (RELU) v = fmaxf(v, 0.f);
                store_out(C, ((size_t)m * row_mul + row_add) * (size_t)N + n, v);
            }
        }
    }
}

// ---------- graph stage: ONE WAVE PER GRAPH, MFMA for all K=512 contractions ----------
// s = x x^T        : A-frag == B-frag == x[lane&15][quad*8+j] per k-step (verified layout)
// t1/t3 = x@W      : B-frags from pre-transposed bf16 W1t/W3t [32,512]; each wave reads
//                    each weight matrix exactly once (kills the 16x redundant re-read).
// Output: cbuf[g][n] = relu(0.5*(omean + gmean)), gmean via colsum collapse.
__global__ __launch_bounds__(64)
void graph_mfma(const ushort_t* __restrict__ obj,
                const ushort_t* __restrict__ W1t, const float* __restrict__ b1,
                const ushort_t* __restrict__ W2b, const float* __restrict__ b2,
                const ushort_t* __restrict__ W3t, const float* __restrict__ b3,
                const ushort_t* __restrict__ W4b, const float* __restrict__ b4,
                ushort_t* __restrict__ cbuf)
{
    __shared__ float ssb[16 * 17];    // s, then exp(s - rowmax)
    __shared__ float adjt[16 * 20];   // adjt[j][i] = adj[i][j]  (float4-aligned rows)
    __shared__ float t1s[16 * 36];    // t1[m][n]
    __shared__ float t3s[16 * 36];
    __shared__ float x1s[16 * 36];    // relu(adj@t1+b1)
    __shared__ float y2s[16 * 36];    // relu(adj@t3+b3)
    __shared__ float y22s[16 * 17];
    __shared__ float a3t[16 * 20];    // adj3 transposed
    __shared__ float dv[16], dv3[16], nrm[16], cA[16], cA3[16];
    __shared__ float zc1[32], zc4[32];

    const int lane = threadIdx.x;
    const int r = lane & 15, fq = lane >> 4;
    const ushort_t* xg = obj + (size_t)blockIdx.x * 8192;   // 16 rows x 512

    // x fragments (held in regs, reused for s and t1/t3)
    short8 xf[16];
#pragma unroll
    for (int kk = 0; kk < 16; kk++)
        xf[kk] = *(const short8*)(xg + r * 512 + kk * 32 + fq * 8);

    // s = x x^T  (16 MFMAs, identical A/B frags)
    f32x4 sacc = (f32x4){0.f, 0.f, 0.f, 0.f};
#pragma unroll
    for (int kk = 0; kk < 16; kk++)
        sacc = __builtin_amdgcn_mfma_f32_16x16x32_bf16(xf[kk], xf[kk], sacc, 0, 0, 0);

    // t1 = x@W1 (n-tiles 0,1), t3 = x@W3
    f32x4 a10 = (f32x4){0.f,0.f,0.f,0.f}, a11 = a10, a30 = a10, a31 = a10;
#pragma unroll
    for (int kk = 0; kk < 16; kk++) {
        const short8 w10 = *(const short8*)(W1t + (size_t)(r)      * 512 + kk * 32 + fq * 8);
        const short8 w11 = *(const short8*)(W1t + (size_t)(16 + r) * 512 + kk * 32 + fq * 8);
        const short8 w30 = *(const short8*)(W3t + (size_t)(r)      * 512 + kk * 32 + fq * 8);
        const short8 w31 = *(const short8*)(W3t + (size_t)(16 + r) * 512 + kk * 32 + fq * 8);
        a10 = __builtin_amdgcn_mfma_f32_16x16x32_bf16(xf[kk], w10, a10, 0, 0, 0);
        a11 = __builtin_amdgcn_mfma_f32_16x16x32_bf16(xf[kk], w11, a11, 0, 0, 0);
        a30 = __builtin_amdgcn_mfma_f32_16x16x32_bf16(xf[kk], w30, a30, 0, 0, 0);
        a31 = __builtin_amdgcn_mfma_f32_16x16x32_bf16(xf[kk], w31, a31, 0, 0, 0);
    }

    // C-layout: row m = fq*4+i, col n = lane&15 (+16 per n-tile)
#pragma unroll
    for (int i = 0; i < 4; i++) {
        const int m = fq * 4 + i;
        ssb[m * 17 + r] = sacc[i];
        t1s[m * 36 + r]      = a10[i];
        t1s[m * 36 + 16 + r] = a11[i];
        t3s[m * 36 + r]      = a30[i];
        t3s[m * 36 + 16 + r] = a31[i];
    }
    __syncthreads();

    // softmax rows (lanes 0..15)
    if (lane < 16) {
        float m = ssb[lane * 17];
#pragma unroll
        for (int j = 1; j < 16; j++) m = fmaxf(m, ssb[lane * 17 + j]);
        float s = 0.f;
#pragma unroll
        for (int j = 0; j < 16; j++) {
            const float e = expf(ssb[lane * 17 + j] - m);
            ssb[lane * 17 + j] = e; s += e;
        }
        dv[lane] = rsqrtf(s);
    }
    __syncthreads();

    // adjt[j][i] = e[i][j]*dv[i]*dv[j]
    {
        const float di = dv[r];
#pragma unroll
        for (int p = 0; p < 4; p++) {
            const int j = fq * 4 + p;
            adjt[j * 20 + r] = ssb[r * 17 + j] * di * dv[j];
        }
    }
    __syncthreads();

    // cA[t] = colsum(adj)
    if (lane < 16) {
        float s = 0.f;
#pragma unroll
        for (int i = 0; i < 16; i++) s += adjt[lane * 20 + i];
        cA[lane] = s;
    }

    // x1 = relu(adj@t1+b1), y2 = relu(adj@t3+b3): lane -> col c, rows hi*8..hi*8+7
    {
        const int c = lane & 31, hi = lane >> 5;
        const float bb1 = b1[c], bb3 = b3[c];
        float ax[8], ay[8];
#pragma unroll
        for (int i = 0; i < 8; i++) { ax[i] = bb1; ay[i] = bb3; }
#pragma unroll
        for (int j = 0; j < 16; j++) {
            const float t1v = t1s[j * 36 + c], t3v = t3s[j * 36 + c];
            const float4 p = *(const float4*)&adjt[j * 20 + hi * 8];
            const float4 q = *(const float4*)&adjt[j * 20 + hi * 8 + 4];
            ax[0] = fmaf(p.x, t1v, ax[0]); ax[1] = fmaf(p.y, t1v, ax[1]);
            ax[2] = fmaf(p.z, t1v, ax[2]); ax[3] = fmaf(p.w, t1v, ax[3]);
            ax[4] = fmaf(q.x, t1v, ax[4]); ax[5] = fmaf(q.y, t1v, ax[5]);
            ax[6] = fmaf(q.z, t1v, ax[6]); ax[7] = fmaf(q.w, t1v, ax[7]);
            ay[0] = fmaf(p.x, t3v, ay[0]); ay[1] = fmaf(p.y, t3v, ay[1]);
            ay[2] = fmaf(p.z, t3v, ay[2]); ay[3] = fmaf(p.w, t3v, ay[3]);
            ay[4] = fmaf(q.x, t3v, ay[4]); ay[5] = fmaf(q.y, t3v, ay[5]);
            ay[6] = fmaf(q.z, t3v, ay[6]); ay[7] = fmaf(q.w, t3v, ay[7]);
        }
#pragma unroll
        for (int i = 0; i < 8; i++) {
            x1s[(hi * 8 + i) * 36 + c] = fmaxf(ax[i], 0.f);
            y2s[(hi * 8 + i) * 36 + c] = fmaxf(ay[i], 0.f);
        }
    }
    __syncthreads();

    // y22 = y2 y2^T: lane -> row i2 = lane>>2, cols j0..j0+3
    {
        const int i2 = lane >> 2, j0 = (lane & 3) * 4;
        float a4[4] = {0.f, 0.f, 0.f, 0.f};
#pragma unroll
        for (int k4 = 0; k4 < 8; k4++) {
            const float4 yi = *(const float4*)&y2s[i2 * 36 + k4 * 4];
#pragma unroll
            for (int p = 0; p < 4; p++) {
                const float4 yj = *(const float4*)&y2s[(j0 + p) * 36 + k4 * 4];
                a4[p] = fmaf(yi.x, yj.x, a4[p]); a4[p] = fmaf(yi.y, yj.y, a4[p]);
                a4[p] = fmaf(yi.z, yj.z, a4[p]); a4[p] = fmaf(yi.w, yj.w, a4[p]);
            }
        }
#pragma unroll
        for (int p = 0; p < 4; p++) y22s[i2 * 17 + j0 + p] = a4[p];
    }
    __syncthreads();

    if (lane < 16) {
        float sq = 0.f;
#pragma unroll
        for (int j = 0; j < 16; j++) { const float v = y22s[lane * 17 + j]; sq = fmaf(v, v, sq); }
        nrm[lane] = sqrtf(sq);
    }
    __syncthreads();

    // a3t[j][i] = 1 + y22[i][j]/(nrm_i*nrm_j)
    {
        const float ni = nrm[r];
#pragma unroll
        for (int p = 0; p < 4; p++) {
            const int j = fq * 4 + p;
            a3t[j * 20 + r] = 1.0f + y22s[r * 17 + j] / (ni * nrm[j]);
        }
    }
    __syncthreads();

    // d3[i] = rsqrt(rowsum adj3) = rsqrt(sum_j a3t[j][i])
    if (lane < 16) {
        float s = 0.f;
#pragma unroll
        for (int j = 0; j < 16; j++) s += a3t[j * 20 + lane];
        dv3[lane] = rsqrtf(s);
    }
    __syncthreads();

    // cA3[t] = colsum(adjh3) = dv3[t] * sum_i a3t[t][i]*dv3[i]
    if (lane < 16) {
        float s = 0.f;
#pragma unroll
        for (int i = 0; i < 16; i++) s = fmaf(a3t[lane * 20 + i], dv3[i], s);
        cA3[lane] = s * dv3[lane];
    }
    __syncthreads();

    // zc1[k] = sum_j cA[j]*x1[j][k], zc4[k] = sum_j cA3[j]*y2[j][k]  (lanes 0..31)
    if (lane < 32) {
        float s1 = 0.f, s4 = 0.f;
#pragma unroll
        for (int j = 0; j < 16; j++) {
            s1 = fmaf(cA[j],  x1s[j * 36 + lane], s1);
            s4 = fmaf(cA3[j], y2s[j * 36 + lane], s4);
        }
        zc1[lane] = s1; zc4[lane] = s4;
    }
    __syncthreads();

    // final: 8 cols per lane: cbuf = relu(0.5*(omean + gmean))
    {
        float om[8] = {0,0,0,0,0,0,0,0};
#pragma unroll
        for (int m = 0; m < 16; m++) {
            const uint4 q = *(const uint4*)(xg + m * 512 + lane * 8);
            om[0] += bflo(q.x); om[1] += bfhi(q.x);
            om[2] += bflo(q.y); om[3] += bfhi(q.y);
            om[4] += bflo(q.z); om[5] += bfhi(q.z);
            om[6] += bflo(q.w); om[7] += bfhi(q.w);
        }
        float gm[8] = {0,0,0,0,0,0,0,0};
        for (int k = 0; k < 32; k++) {
            const float z1 = zc1[k], z4 = zc4[k];
            const uint4 w2 = *(const uint4*)(W2b + (size_t)k * 512 + lane * 8);
            const uint4 w4 = *(const uint4*)(W4b + (size_t)k * 512 + lane * 8);
            gm[0] = fmaf(z1, bflo(w2.x), gm[0]); gm[0] = fmaf(z4, bflo(w4.x), gm[0]);
            gm[1] = fmaf(z1, bfhi(w2.x), gm[1]); gm[1] = fmaf(z4, bfhi(w4.x), gm[1]);
            gm[2] = fmaf(z1, bflo(w2.y), gm[2]); gm[2] = fmaf(z4, bflo(w4.y), gm[2]);
            gm[3] = fmaf(z1, bfhi(w2.y), gm[3]); gm[3] = fmaf(z4, bfhi(w4.y), gm[3]);
            gm[4] = fmaf(z1, bflo(w2.z), gm[4]); gm[4] = fmaf(z4, bflo(w4.z), gm[4]);
            gm[5] = fmaf(z1, bfhi(w2.z), gm[5]); gm[5] = fmaf(z4, bfhi(w4.z), gm[5]);
            gm[6] = fmaf(z1, bflo(w2.w), gm[6]); gm[6] = fmaf(z4, bflo(w4.w), gm[6]);
            gm[7] = fmaf(z1, bfhi(w2.w), gm[7]); gm[7] = fmaf(z4, bfhi(w4.w), gm[7]);
        }
        const float4 b2a = *(const float4*)&b2[lane * 8];
        const float4 b2b = *(const float4*)&b2[lane * 8 + 4];
        const float4 b4a = *(const float4*)&b4[lane * 8];
        const float4 b4b = *(const float4*)&b4[lane * 8 + 4];
        const float bs[8] = { b2a.x + b4a.x, b2a.y + b4a.y, b2a.z + b4a.z, b2a.w + b4a.w,
                              b2b.x + b4b.x, b2b.y + b4b.y, b2b.z + b4b.z, b2b.w + b4b.w };
        ushort_t pk[8];
#pragma unroll
        for (int c = 0; c < 8; c++) {
            const float gmean = 0.5f * bs[c] + gm[c] * (1.0f / 32.0f);
            const float feat  = 0.5f * (om[c] * 0.0625f + gmean);
            pk[c] = f2bf(fmaxf(feat, 0.f));
        }
        *(uint4*)(cbuf + (size_t)blockIdx.x * 512 + lane * 8) = *(uint4*)pk;
    }
}

// ---------- final mean over T=64 (outT pitch 512, first 500 valid) ----------
__global__ __launch_bounds__(256)
void reduce_mean_T(const float* __restrict__ outT, float* __restrict__ out)
{
    const int idx = blockIdx.x * 256 + threadIdx.x;
    if (idx >= 32 * 500) return;
    const int n = idx / 500, j = idx - n * 500;
    const float* p = outT + (size_t)n * 64 * 512 + j;
    float s = 0.f;
#pragma unroll 8
    for (int tt = 0; tt < 64; tt++) s += p[tt * 512];
    out[idx] = s * (1.0f / 64.0f);
}

// ---------- launcher ----------
extern "C" void kernel_launch(void* const* d_in, const int* in_sizes, int n_in,
                              void* d_out, int out_size, void* d_ws, size_t ws_size,
                              hipStream_t stream)
{
    const float* object_raw = (const float*)d_in[0];
    const float* action_raw = (const float*)d_in[1];
    const float* W_obj = (const float*)d_in[2];
    const float* b_obj = (const float*)d_in[3];
    const float* W_act = (const float*)d_in[4];
    const float* b_act = (const float*)d_in[5];
    const float* gc1_W = (const float*)d_in[6];
    const float* gc1_b = (const float*)d_in[7];
    const float* gc2_W = (const float*)d_in[8];
    const float* gc2_b = (const float*)d_in[9];
    const float* gc3_W = (const float*)d_in[10];
    const float* gc3_b = (const float*)d_in[11];
    const float* gc4_W = (const float*)d_in[12];
    const float* gc4_b = (const float*)d_in[13];
    const float* fc1_W = (const float*)d_in[14];
    const float* fc1_b = (const float*)d_in[15];
    const float* clf_W = (const float*)d_in[16];
    const float* clf_b = (const float*)d_in[17];

    // ws layout (bytes), peak ~67.3MB (68MB budget proven in round 2):
    //  [0,32M):  objA (bf16, dead after obj GEMM) -> then actA@0, cbuf@2M, c2@4M, outT@8M
    //  [32M,64M): obj_bf
    //  [64M,67M): WobjT | WactT | fc1T | clfT
    //  [67M, +256K): W1t | W3t | W2bf | W4bf (32KB each)
    char* ws = (char*)d_ws;
    const size_t MB = 1024 * 1024;
    ushort_t* objA   = (ushort_t*)(ws);
    ushort_t* actA   = (ushort_t*)(ws);
    ushort_t* cbuf   = (ushort_t*)(ws + 2 * MB);
    ushort_t* c2     = (ushort_t*)(ws + 4 * MB);
    float*    outT   = (float*)   (ws + 8 * MB);
    ushort_t* obj_bf = (ushort_t*)(ws + 32 * MB);
    ushort_t* WobjT  = (ushort_t*)(ws + 64 * MB);
    ushort_t* WactT  = (ushort_t*)(ws + 64 * MB + 512 * 1024);
    ushort_t* fc1T   = (ushort_t*)(ws + 65 * MB);
    ushort_t* clfT   = (ushort_t*)(ws + 66 * MB);
    ushort_t* W1t    = (ushort_t*)(ws + 67 * MB);
    ushort_t* W3t    = (ushort_t*)(ws + 67 * MB + 64 * 1024);
    ushort_t* W2bf   = (ushort_t*)(ws + 67 * MB + 128 * 1024);
    ushort_t* W4bf   = (ushort_t*)(ws + 67 * MB + 192 * 1024);

    // weight transposes / converts
    transpose_cvt<<<dim3(16, 16), dim3(32, 8), 0, stream>>>(W_obj, WobjT, 512, 512, 512);
    transpose_cvt<<<dim3(16, 16), dim3(32, 8), 0, stream>>>(W_act, WactT, 512, 512, 512);
    transpose_cvt<<<dim3(32, 16), dim3(32, 8), 0, stream>>>(fc1_W, fc1T, 512, 1024, 1024);
    transpose_cvt<<<dim3(16, 32), dim3(32, 8), 0, stream>>>(clf_W, clfT, 1024, 500, 512);
    transpose_cvt<<<dim3(1, 16),  dim3(32, 8), 0, stream>>>(gc1_W, W1t, 512, 32, 32);
    transpose_cvt<<<dim3(1, 16),  dim3(32, 8), 0, stream>>>(gc3_W, W3t, 512, 32, 32);
    cvt_bf16x8<<<dim3(8), 256, 0, stream>>>(gc2_W, W2bf, 32 * 512 / 8);
    cvt_bf16x8<<<dim3(8), 256, 0, stream>>>(gc4_W, W4bf, 32 * 512 / 8);

    // obj path
    cvt_bf16x8<<<dim3(8192), 256, 0, stream>>>(object_raw, objA, 32768 * 512 / 8);
    gemm_mfma<1, ushort_t><<<dim3(4, 256), 256, 0, stream>>>(
        objA, WobjT, b_obj, obj_bf, 32768, 512, 512, 512, 1, 0);

    // act path (objA region now dead -> actA at offset 0)
    cvt_bf16x8<<<dim3(512), 256, 0, stream>>>(action_raw, actA, 2048 * 512 / 8);
    gemm_mfma<1, ushort_t><<<dim3(4, 16), 256, 0, stream>>>(
        actA, WactT, b_act, obj_bf, 2048, 512, 512, 512, 16, 8);

    // graph stage: one wave per graph
    graph_mfma<<<dim3(2048), 64, 0, stream>>>(
        obj_bf, W1t, gc1_b, W2bf, gc2_b, W3t, gc3_b, W4bf, gc4_b, cbuf);

    // fc1 + clf
    gemm_mfma<1, ushort_t><<<dim3(8, 16), 256, 0, stream>>>(
        cbuf, fc1T, fc1_b, c2, 2048, 1024, 512, 1024, 1, 0);
    gemm_mfma<0, float><<<dim3(4, 16), 256, 0, stream>>>(
        c2, clfT, clf_b, outT, 2048, 512, 1024, 500, 1, 0);

    // mean over T
    reduce_mean_T<<<dim3(63), 256, 0, stream>>>(outT, (float*)d_out);
}

// Round 5
// 271.211 us; speedup vs baseline: 2.4444x; 1.0568x over previous
//
#include <hip/hip_runtime.h>
#include <hip/hip_bf16.h>

using ushort_t = unsigned short;
using f32x4  = __attribute__((ext_vector_type(4))) float;
using short8 = __attribute__((ext_vector_type(8))) short;

// ---------- bf16 helpers ----------
__device__ __forceinline__ float bflo(unsigned p) {
    union { unsigned u; float f; } x; x.u = p << 16; return x.f;
}
__device__ __forceinline__ float bfhi(unsigned p) {
    union { unsigned u; float f; } x; x.u = p & 0xffff0000u; return x.f;
}
__device__ __forceinline__ ushort_t f2bf(float f) {
    __hip_bfloat16 h = __float2bfloat16(f);   // RTNE
    return *(ushort_t*)&h;
}
__device__ __forceinline__ unsigned pk2bf(float lo, float hi) {
    __hip_bfloat162 h = __float22bfloat162_rn({lo, hi});  // RTNE, packed
    return *(unsigned*)&h;
}

// ---------- combined weight prep: 6 transposes + 2 converts in ONE dispatch ----------
// transpose tiles use (32,8) thread view; cvt blocks use flat 256.
__device__ __forceinline__ void tr_tile(const float* __restrict__ S, ushort_t* __restrict__ D,
                                        int K, int N, int Npad, int bx, int by,
                                        int tx, int ty, float* tile /*32*33*/)
{
    const int k0 = by * 32, n0 = bx * 32;
#pragma unroll
    for (int r = 0; r < 4; r++) {
        const int k = k0 + ty + r * 8, n = n0 + tx;
        tile[(ty + r * 8) * 33 + tx] = (k < K && n < N) ? S[(size_t)k * N + n] : 0.f;
    }
    __syncthreads();
#pragma unroll
    for (int r = 0; r < 4; r++) {
        const int n = n0 + ty + r * 8, k = k0 + tx;
        if (n < Npad && k < K) D[(size_t)n * K + k] = f2bf(tile[tx * 33 + ty + r * 8]);
    }
}

__global__ __launch_bounds__(256)
void prep_weights(const float* __restrict__ Wobj, ushort_t* __restrict__ WobjT,
                  const float* __restrict__ Wact, ushort_t* __restrict__ WactT,
                  const float* __restrict__ fc1W, ushort_t* __restrict__ fc1T,
                  const float* __restrict__ clfW, ushort_t* __restrict__ clfT,
                  const float* __restrict__ gc1W, ushort_t* __restrict__ W1t,
                  const float* __restrict__ gc3W, ushort_t* __restrict__ W3t,
                  const float* __restrict__ gc2W, ushort_t* __restrict__ W2bf,
                  const float* __restrict__ gc4W, ushort_t* __restrict__ W4bf)
{
    __shared__ float tile[32 * 33];
    const int b = blockIdx.x;
    const int t = threadIdx.x;
    const int tx = t & 31, ty = t >> 5;

    if (b < 1568) {
        const float* S; ushort_t* D; int K, N, Npad, nt, l;
        if      (b < 256)  { S = Wobj; D = WobjT; K = 512;  N = 512;  Npad = 512;  nt = 16; l = b; }
        else if (b < 512)  { S = Wact; D = WactT; K = 512;  N = 512;  Npad = 512;  nt = 16; l = b - 256; }
        else if (b < 1024) { S = fc1W; D = fc1T;  K = 512;  N = 1024; Npad = 1024; nt = 32; l = b - 512; }
        else if (b < 1536) { S = clfW; D = clfT;  K = 1024; N = 500;  Npad = 512;  nt = 16; l = b - 1024; }
        else if (b < 1552) { S = gc1W; D = W1t;   K = 512;  N = 32;   Npad = 32;   nt = 1;  l = b - 1536; }
        else               { S = gc3W; D = W3t;   K = 512;  N = 32;   Npad = 32;   nt = 1;  l = b - 1552; }
        tr_tile(S, D, K, N, Npad, l % nt, l / nt, tx, ty, tile);
    } else {
        const float* S = (b < 1576) ? gc2W : gc4W;
        ushort_t* D    = (b < 1576) ? W2bf : W4bf;
        const int i = (b < 1576 ? b - 1568 : b - 1576) * 256 + t;   // < 2048 = 32*512/8
        const float4 x = ((const float4*)S)[2 * i];
        const float4 y = ((const float4*)S)[2 * i + 1];
        unsigned r[4] = { pk2bf(x.x, x.y), pk2bf(x.z, x.w), pk2bf(y.x, y.y), pk2bf(y.z, y.w) };
        ((uint4*)D)[i] = *(uint4*)r;
    }
}

// ---------- staging fragments (A may be fp32 -> inline RTNE cvt at LDS-write) ----------
struct FragBf { uint4 v;
    __device__ __forceinline__ void load(const ushort_t* p) { v = *(const uint4*)p; }
    __device__ __forceinline__ void store(ushort_t* d) { *(uint4*)d = v; } };
struct FragF32 { float4 a, b;
    __device__ __forceinline__ void load(const float* p) { a = *(const float4*)p; b = *(const float4*)(p + 4); }
    __device__ __forceinline__ void store(ushort_t* d) {
        unsigned r[4] = { pk2bf(a.x, a.y), pk2bf(a.z, a.w), pk2bf(b.x, b.y), pk2bf(b.z, b.w) };
        *(uint4*)d = *(uint4*)r; } };
template<typename AT> struct FragOf;
template<> struct FragOf<ushort_t> { using type = FragBf; };
template<> struct FragOf<float>    { using type = FragF32; };

// ---------- MFMA GEMM: C = act(A @ B + bias), software-pipelined K-loop ----------
// A: [M,K] (fp32 or bf16).  Bt: bf16 [N,K].  Tile 128x128, BK=32, 4 waves.
__device__ __forceinline__ void store_out(ushort_t* C, size_t idx, float v) { C[idx] = f2bf(v); }
__device__ __forceinline__ void store_out(float* C, size_t idx, float v)    { C[idx] = v; }

template<int RELU, typename AT, typename OT>
__global__ __launch_bounds__(256)
void gemm_mfma(const AT* __restrict__ A, const ushort_t* __restrict__ Bt,
               const float* __restrict__ bias, OT* __restrict__ C,
               int M, int N, int K, int Nb, int row_mul, int row_add)
{
    using AFrag = typename FragOf<AT>::type;
    __shared__ ushort_t As[128 * 56];
    __shared__ ushort_t Bs[128 * 56];
    const int t = threadIdx.x;
    const int lane = t & 63, w = t >> 6;
    const int bm = blockIdx.y * 128, bn = blockIdx.x * 128;
    const int mb = (w & 1) * 64, nb = (w >> 1) * 64;

    const int r0 = t >> 2, kc0 = t & 3;
    const AT*       Ag = A  + (size_t)(bm + r0) * K + kc0 * 8;
    const ushort_t* Bg = Bt + (size_t)(bn + r0) * K + kc0 * 8;
    const size_t rowskip = (size_t)64 * K;

    f32x4 acc[16];
#pragma unroll
    for (int i = 0; i < 16; i++) acc[i] = (f32x4){0.f, 0.f, 0.f, 0.f};

    const int fr = lane & 15, fq = lane >> 4;

    // prologue: preload k-tile 0
    AFrag a0, a1; uint4 b0, b1;
    a0.load(Ag); a1.load(Ag + rowskip);
    b0 = *(const uint4*)(Bg); b1 = *(const uint4*)(Bg + rowskip);

    for (int k0 = 0; k0 < K; k0 += 32) {
        a0.store(&As[(r0)      * 56 + kc0 * 8]);
        a1.store(&As[(r0 + 64) * 56 + kc0 * 8]);
        *(uint4*)&Bs[(r0)      * 56 + kc0 * 8] = b0;
        *(uint4*)&Bs[(r0 + 64) * 56 + kc0 * 8] = b1;
        __syncthreads();

        // issue next tile's global loads BEFORE the MFMA block (latency hidden by compute)
        if (k0 + 32 < K) {
            a0.load(Ag + k0 + 32); a1.load(Ag + rowskip + k0 + 32);
            b0 = *(const uint4*)(Bg + k0 + 32); b1 = *(const uint4*)(Bg + rowskip + k0 + 32);
        }

        short8 af[4], bf[4];
#pragma unroll
        for (int i = 0; i < 4; i++)
            af[i] = *(const short8*)&As[(mb + i * 16 + fr) * 56 + fq * 8];
#pragma unroll
        for (int j = 0; j < 4; j++)
            bf[j] = *(const short8*)&Bs[(nb + j * 16 + fr) * 56 + fq * 8];
#pragma unroll
        for (int i = 0; i < 4; i++)
#pragma unroll
            for (int j = 0; j < 4; j++)
                acc[i * 4 + j] = __builtin_amdgcn_mfma_f32_16x16x32_bf16(
                    af[i], bf[j], acc[i * 4 + j], 0, 0, 0);
        __syncthreads();
    }

#pragma unroll
    for (int j = 0; j < 4; j++) {
        const int n = bn + nb + j * 16 + fr;
        const float bv = (n < Nb) ? bias[n] : 0.f;
#pragma unroll
        for (int i = 0; i < 4; i++) {
            const f32x4 a = acc[i * 4 + j];
#pragma unroll
            for (int r = 0; r < 4; r++) {
                const int m = bm + mb + i * 16 + fq * 4 + r;
                float v = a[r] + bv;
                if (RELU) v = fmaxf(v, 0.f);
                store_out(C, ((size_t)m * row_mul + row_add) * (size_t)N + n, v);
            }
        }
    }
}

// ---------- graph stage: one wave per graph (unchanged from round 4) ----------
__global__ __launch_bounds__(64)
void graph_mfma(const ushort_t* __restrict__ obj,
                const ushort_t* __restrict__ W1t, const float* __restrict__ b1,
                const ushort_t* __restrict__ W2b, const float* __restrict__ b2,
                const ushort_t* __restrict__ W3t, const float* __restrict__ b3,
                const ushort_t* __restrict__ W4b, const float* __restrict__ b4,
                ushort_t* __restrict__ cbuf)
{
    __shared__ float ssb[16 * 17];
    __shared__ float adjt[16 * 20];
    __shared__ float t1s[16 * 36];
    __shared__ float t3s[16 * 36];
    __shared__ float x1s[16 * 36];
    __shared__ float y2s[16 * 36];
    __shared__ float y22s[16 * 17];
    __shared__ float a3t[16 * 20];
    __shared__ float dv[16], dv3[16], nrm[16], cA[16], cA3[16];
    __shared__ float zc1[32], zc4[32];

    const int lane = threadIdx.x;
    const int r = lane & 15, fq = lane >> 4;
    const ushort_t* xg = obj + (size_t)blockIdx.x * 8192;

    short8 xf[16];
#pragma unroll
    for (int kk = 0; kk < 16; kk++)
        xf[kk] = *(const short8*)(xg + r * 512 + kk * 32 + fq * 8);

    f32x4 sacc = (f32x4){0.f, 0.f, 0.f, 0.f};
#pragma unroll
    for (int kk = 0; kk < 16; kk++)
        sacc = __builtin_amdgcn_mfma_f32_16x16x32_bf16(xf[kk], xf[kk], sacc, 0, 0, 0);

    f32x4 a10 = (f32x4){0.f,0.f,0.f,0.f}, a11 = a10, a30 = a10, a31 = a10;
#pragma unroll
    for (int kk = 0; kk < 16; kk++) {
        const short8 w10 = *(const short8*)(W1t + (size_t)(r)      * 512 + kk * 32 + fq * 8);
        const short8 w11 = *(const short8*)(W1t + (size_t)(16 + r) * 512 + kk * 32 + fq * 8);
        const short8 w30 = *(const short8*)(W3t + (size_t)(r)      * 512 + kk * 32 + fq * 8);
        const short8 w31 = *(const short8*)(W3t + (size_t)(16 + r) * 512 + kk * 32 + fq * 8);
        a10 = __builtin_amdgcn_mfma_f32_16x16x32_bf16(xf[kk], w10, a10, 0, 0, 0);
        a11 = __builtin_amdgcn_mfma_f32_16x16x32_bf16(xf[kk], w11, a11, 0, 0, 0);
        a30 = __builtin_amdgcn_mfma_f32_16x16x32_bf16(xf[kk], w30, a30, 0, 0, 0);
        a31 = __builtin_amdgcn_mfma_f32_16x16x32_bf16(xf[kk], w31, a31, 0, 0, 0);
    }

#pragma unroll
    for (int i = 0; i < 4; i++) {
        const int m = fq * 4 + i;
        ssb[m * 17 + r] = sacc[i];
        t1s[m * 36 + r]      = a10[i];
        t1s[m * 36 + 16 + r] = a11[i];
        t3s[m * 36 + r]      = a30[i];
        t3s[m * 36 + 16 + r] = a31[i];
    }
    __syncthreads();

    if (lane < 16) {
        float m = ssb[lane * 17];
#pragma unroll
        for (int j = 1; j < 16; j++) m = fmaxf(m, ssb[lane * 17 + j]);
        float s = 0.f;
#pragma unroll
        for (int j = 0; j < 16; j++) {
            const float e = expf(ssb[lane * 17 + j] - m);
            ssb[lane * 17 + j] = e; s += e;
        }
        dv[lane] = rsqrtf(s);
    }
    __syncthreads();

    {
        const float di = dv[r];
#pragma unroll
        for (int p = 0; p < 4; p++) {
            const int j = fq * 4 + p;
            adjt[j * 20 + r] = ssb[r * 17 + j] * di * dv[j];
        }
    }
    __syncthreads();

    if (lane < 16) {
        float s = 0.f;
#pragma unroll
        for (int i = 0; i < 16; i++) s += adjt[lane * 20 + i];
        cA[lane] = s;
    }

    {
        const int c = lane & 31, hi = lane >> 5;
        const float bb1 = b1[c], bb3 = b3[c];
        float ax[8], ay[8];
#pragma unroll
        for (int i = 0; i < 8; i++) { ax[i] = bb1; ay[i] = bb3; }
#pragma unroll
        for (int j = 0; j < 16; j++) {
            const float t1v = t1s[j * 36 + c], t3v = t3s[j * 36 + c];
            const float4 p = *(const float4*)&adjt[j * 20 + hi * 8];
            const float4 q = *(const float4*)&adjt[j * 20 + hi * 8 + 4];
            ax[0] = fmaf(p.x, t1v, ax[0]); ax[1] = fmaf(p.y, t1v, ax[1]);
            ax[2] = fmaf(p.z, t1v, ax[2]); ax[3] = fmaf(p.w, t1v, ax[3]);
            ax[4] = fmaf(q.x, t1v, ax[4]); ax[5] = fmaf(q.y, t1v, ax[5]);
            ax[6] = fmaf(q.z, t1v, ax[6]); ax[7] = fmaf(q.w, t1v, ax[7]);
            ay[0] = fmaf(p.x, t3v, ay[0]); ay[1] = fmaf(p.y, t3v, ay[1]);
            ay[2] = fmaf(p.z, t3v, ay[2]); ay[3] = fmaf(p.w, t3v, ay[3]);
            ay[4] = fmaf(q.x, t3v, ay[4]); ay[5] = fmaf(q.y, t3v, ay[5]);
            ay[6] = fmaf(q.z, t3v, ay[6]); ay[7] = fmaf(q.w, t3v, ay[7]);
        }
#pragma unroll
        for (int i = 0; i < 8; i++) {
            x1s[(hi * 8 + i) * 36 + c] = fmaxf(ax[i], 0.f);
            y2s[(hi * 8 + i) * 36 + c] = fmaxf(ay[i], 0.f);
        }
    }
    __syncthreads();

    {
        const int i2 = lane >> 2, j0 = (lane & 3) * 4;
        float a4[4] = {0.f, 0.f, 0.f, 0.f};
#pragma unroll
        for (int k4 = 0; k4 < 8; k4++) {
            const float4 yi = *(const float4*)&y2s[i2 * 36 + k4 * 4];
#pragma unroll
            for (int p = 0; p < 4; p++) {
                const float4 yj = *(const float4*)&y2s[(j0 + p) * 36 + k4 * 4];
                a4[p] = fmaf(yi.x, yj.x, a4[p]); a4[p] = fmaf(yi.y, yj.y, a4[p]);
                a4[p] = fmaf(yi.z, yj.z, a4[p]); a4[p] = fmaf(yi.w, yj.w, a4[p]);
            }
        }
#pragma unroll
        for (int p = 0; p < 4; p++) y22s[i2 * 17 + j0 + p] = a4[p];
    }
    __syncthreads();

    if (lane < 16) {
        float sq = 0.f;
#pragma unroll
        for (int j = 0; j < 16; j++) { const float v = y22s[lane * 17 + j]; sq = fmaf(v, v, sq); }
        nrm[lane] = sqrtf(sq);
    }
    __syncthreads();

    {
        const float ni = nrm[r];
#pragma unroll
        for (int p = 0; p < 4; p++) {
            const int j = fq * 4 + p;
            a3t[j * 20 + r] = 1.0f + y22s[r * 17 + j] / (ni * nrm[j]);
        }
    }
    __syncthreads();

    if (lane < 16) {
        float s = 0.f;
#pragma unroll
        for (int j = 0; j < 16; j++) s += a3t[j * 20 + lane];
        dv3[lane] = rsqrtf(s);
    }
    __syncthreads();

    if (lane < 16) {
        float s = 0.f;
#pragma unroll
        for (int i = 0; i < 16; i++) s = fmaf(a3t[lane * 20 + i], dv3[i], s);
        cA3[lane] = s * dv3[lane];
    }
    __syncthreads();

    if (lane < 32) {
        float s1 = 0.f, s4 = 0.f;
#pragma unroll
        for (int j = 0; j < 16; j++) {
            s1 = fmaf(cA[j],  x1s[j * 36 + lane], s1);
            s4 = fmaf(cA3[j], y2s[j * 36 + lane], s4);
        }
        zc1[lane] = s1; zc4[lane] = s4;
    }
    __syncthreads();

    {
        float om[8] = {0,0,0,0,0,0,0,0};
#pragma unroll
        for (int m = 0; m < 16; m++) {
            const uint4 q = *(const uint4*)(xg + m * 512 + lane * 8);
            om[0] += bflo(q.x); om[1] += bfhi(q.x);
            om[2] += bflo(q.y); om[3] += bfhi(q.y);
            om[4] += bflo(q.z); om[5] += bfhi(q.z);
            om[6] += bflo(q.w); om[7] += bfhi(q.w);
        }
        float gm[8] = {0,0,0,0,0,0,0,0};
        for (int k = 0; k < 32; k++) {
            const float z1 = zc1[k], z4 = zc4[k];
            const uint4 w2 = *(const uint4*)(W2b + (size_t)k * 512 + lane * 8);
            const uint4 w4 = *(const uint4*)(W4b + (size_t)k * 512 + lane * 8);
            gm[0] = fmaf(z1, bflo(w2.x), gm[0]); gm[0] = fmaf(z4, bflo(w4.x), gm[0]);
            gm[1] = fmaf(z1, bfhi(w2.x), gm[1]); gm[1] = fmaf(z4, bfhi(w4.x), gm[1]);
            gm[2] = fmaf(z1, bflo(w2.y), gm[2]); gm[2] = fmaf(z4, bflo(w4.y), gm[2]);
            gm[3] = fmaf(z1, bfhi(w2.y), gm[3]); gm[3] = fmaf(z4, bfhi(w4.y), gm[3]);
            gm[4] = fmaf(z1, bflo(w2.z), gm[4]); gm[4] = fmaf(z4, bflo(w4.z), gm[4]);
            gm[5] = fmaf(z1, bfhi(w2.z), gm[5]); gm[5] = fmaf(z4, bfhi(w4.z), gm[5]);
            gm[6] = fmaf(z1, bflo(w2.w), gm[6]); gm[6] = fmaf(z4, bflo(w4.w), gm[6]);
            gm[7] = fmaf(z1, bfhi(w2.w), gm[7]); gm[7] = fmaf(z4, bfhi(w4.w), gm[7]);
        }
        const float4 b2a = *(const float4*)&b2[lane * 8];
        const float4 b2b = *(const float4*)&b2[lane * 8 + 4];
        const float4 b4a = *(const float4*)&b4[lane * 8];
        const float4 b4b = *(const float4*)&b4[lane * 8 + 4];
        const float bs[8] = { b2a.x + b4a.x, b2a.y + b4a.y, b2a.z + b4a.z, b2a.w + b4a.w,
                              b2b.x + b4b.x, b2b.y + b4b.y, b2b.z + b4b.z, b2b.w + b4b.w };
        ushort_t pk[8];
#pragma unroll
        for (int c = 0; c < 8; c++) {
            const float gmean = 0.5f * bs[c] + gm[c] * (1.0f / 32.0f);
            const float feat  = 0.5f * (om[c] * 0.0625f + gmean);
            pk[c] = f2bf(fmaxf(feat, 0.f));
        }
        *(uint4*)(cbuf + (size_t)blockIdx.x * 512 + lane * 8) = *(uint4*)pk;
    }
}

// ---------- cmean[32,1024] = mean over T=64 of c2[2048,1024] (bf16 in, fp32 out) ----------
__global__ __launch_bounds__(256)
void mean_c2(const ushort_t* __restrict__ c2, float* __restrict__ cmean)
{
    const int idx = blockIdx.x * 256 + threadIdx.x;   // 32768 = 32*1024
    const int n = idx >> 10, k = idx & 1023;
    const ushort_t* p = c2 + (size_t)n * 64 * 1024 + k;
    float s = 0.f;
#pragma unroll 8
    for (int tt = 0; tt < 64; tt++) {
        union { unsigned u; float f; } x; x.u = ((unsigned)p[tt * 1024]) << 16;
        s += x.f;
    }
    cmean[idx] = s * (1.0f / 64.0f);
}

// ---------- tiny clf: out[n,j] = cmean[n,:] . clfT[j,:] + clf_b[j]  (mean-before-affine) ----------
__global__ __launch_bounds__(256)
void clf_small(const float* __restrict__ cmean, const ushort_t* __restrict__ clfT,
               const float* __restrict__ clf_b, float* __restrict__ out)
{
    const int t = threadIdx.x;
    const int n = t & 31, jo = t >> 5;
    const int j = blockIdx.x * 8 + jo;                // 63 blocks * 8 = 504 >= 500
    const float4* cm = (const float4*)(cmean + (size_t)n * 1024);
    const uint2*  wr = (const uint2*)(clfT + (size_t)(j < 500 ? j : 499) * 1024);
    float acc = 0.f;
#pragma unroll 4
    for (int k4 = 0; k4 < 256; k4++) {
        const float4 c = cm[k4];
        const uint2  w = wr[k4];
        acc = fmaf(c.x, bflo(w.x), acc);
        acc = fmaf(c.y, bfhi(w.x), acc);
        acc = fmaf(c.z, bflo(w.y), acc);
        acc = fmaf(c.w, bfhi(w.y), acc);
    }
    if (j < 500) out[(size_t)n * 500 + j] = acc + clf_b[j];
}

// ---------- launcher ----------
extern "C" void kernel_launch(void* const* d_in, const int* in_sizes, int n_in,
                              void* d_out, int out_size, void* d_ws, size_t ws_size,
                              hipStream_t stream)
{
    const float* object_raw = (const float*)d_in[0];
    const float* action_raw = (const float*)d_in[1];
    const float* W_obj = (const float*)d_in[2];
    const float* b_obj = (const float*)d_in[3];
    const float* W_act = (const float*)d_in[4];
    const float* b_act = (const float*)d_in[5];
    const float* gc1_W = (const float*)d_in[6];
    const float* gc1_b = (const float*)d_in[7];
    const float* gc2_W = (const float*)d_in[8];
    const float* gc2_b = (const float*)d_in[9];
    const float* gc3_W = (const float*)d_in[10];
    const float* gc3_b = (const float*)d_in[11];
    const float* gc4_W = (const float*)d_in[12];
    const float* gc4_b = (const float*)d_in[13];
    const float* fc1_W = (const float*)d_in[14];
    const float* fc1_b = (const float*)d_in[15];
    const float* clf_W = (const float*)d_in[16];
    const float* clf_b = (const float*)d_in[17];

    // ws layout (bytes), peak ~42.2 MB:
    char* ws = (char*)d_ws;
    const size_t MB = 1024 * 1024;
    ushort_t* obj_bf = (ushort_t*)(ws);                       // 32 MB
    ushort_t* cbuf   = (ushort_t*)(ws + 32 * MB);             // 2 MB
    ushort_t* c2     = (ushort_t*)(ws + 34 * MB);             // 4 MB
    float*    cmean  = (float*)   (ws + 38 * MB);             // 128 KB
    ushort_t* WobjT  = (ushort_t*)(ws + 39 * MB);             // 512 KB
    ushort_t* WactT  = (ushort_t*)(ws + 39 * MB + 512 * 1024);
    ushort_t* fc1T   = (ushort_t*)(ws + 40 * MB);             // 1 MB
    ushort_t* clfT   = (ushort_t*)(ws + 41 * MB);             // 1 MB (512x1024 bf16)
    ushort_t* W1t    = (ushort_t*)(ws + 42 * MB);
    ushort_t* W3t    = (ushort_t*)(ws + 42 * MB + 32 * 1024);
    ushort_t* W2bf   = (ushort_t*)(ws + 42 * MB + 64 * 1024);
    ushort_t* W4bf   = (ushort_t*)(ws + 42 * MB + 96 * 1024);

    // 1. all weight preps in one dispatch (1568 transpose tiles + 16 cvt blocks)
    prep_weights<<<dim3(1584), 256, 0, stream>>>(
        W_obj, WobjT, W_act, WactT, fc1_W, fc1T, clf_W, clfT,
        gc1_W, W1t, gc3_W, W3t, gc2_W, W2bf, gc4_W, W4bf);

    // 2. obj = relu(object_raw @ W_obj + b_obj), fp32 A with fused cvt -> bf16 out
    gemm_mfma<1, float, ushort_t><<<dim3(4, 256), 256, 0, stream>>>(
        object_raw, WobjT, b_obj, obj_bf, 32768, 512, 512, 512, 1, 0);

    // 3. act scattered into obj rows g*16+8
    gemm_mfma<1, float, ushort_t><<<dim3(4, 16), 256, 0, stream>>>(
        action_raw, WactT, b_act, obj_bf, 2048, 512, 512, 512, 16, 8);

    // 4. graph stage: one wave per graph
    graph_mfma<<<dim3(2048), 64, 0, stream>>>(
        obj_bf, W1t, gc1_b, W2bf, gc2_b, W3t, gc3_b, W4bf, gc4_b, cbuf);

    // 5. c2 = relu(cbuf @ fc1_W + fc1_b)
    gemm_mfma<1, ushort_t, ushort_t><<<dim3(8, 16), 256, 0, stream>>>(
        cbuf, fc1T, fc1_b, c2, 2048, 1024, 512, 1024, 1, 0);

    // 6. cmean = mean over T (affine clf commutes with mean)
    mean_c2<<<dim3(128), 256, 0, stream>>>(c2, cmean);

    // 7. out = cmean @ clf_W + clf_b   [32,500]
    clf_small<<<dim3(63), 256, 0, stream>>>(cmean, clfT, clf_b, (float*)d_out);
}

// Round 6
// 267.538 us; speedup vs baseline: 2.4779x; 1.0137x over previous
//
#include <hip/hip_runtime.h>
#include <hip/hip_bf16.h>

using ushort_t = unsigned short;
using f32x4  = __attribute__((ext_vector_type(4))) float;
using short8 = __attribute__((ext_vector_type(8))) short;

// ---------- bf16 helpers ----------
__device__ __forceinline__ float bflo(unsigned p) {
    union { unsigned u; float f; } x; x.u = p << 16; return x.f;
}
__device__ __forceinline__ float bfhi(unsigned p) {
    union { unsigned u; float f; } x; x.u = p & 0xffff0000u; return x.f;
}
__device__ __forceinline__ ushort_t f2bf(float f) {
    __hip_bfloat16 h = __float2bfloat16(f);   // RTNE
    return *(ushort_t*)&h;
}
__device__ __forceinline__ unsigned pk2bf(float lo, float hi) {
    __hip_bfloat162 h = __float22bfloat162_rn({lo, hi});  // RTNE, packed
    return *(unsigned*)&h;
}

// ---------- async global->LDS DMA, 16B per lane (m97 pattern) ----------
// LDS dst = wave-uniform base + lane*16 (HW rule); global addr is per-lane.
typedef __attribute__((address_space(1))) void glb_void;
typedef __attribute__((address_space(3))) void lds_void;
__device__ __forceinline__ void dma16(const void* g, void* l) {
    __builtin_amdgcn_global_load_lds((glb_void*)(unsigned long long)(uintptr_t)g,
                                     (lds_void*)(unsigned)(uintptr_t)l, 16, 0, 0);
}

// ---------- combined weight prep (unchanged from round 5) ----------
__device__ __forceinline__ void tr_tile(const float* __restrict__ S, ushort_t* __restrict__ D,
                                        int K, int N, int Npad, int bx, int by,
                                        int tx, int ty, float* tile /*32*33*/)
{
    const int k0 = by * 32, n0 = bx * 32;
#pragma unroll
    for (int r = 0; r < 4; r++) {
        const int k = k0 + ty + r * 8, n = n0 + tx;
        tile[(ty + r * 8) * 33 + tx] = (k < K && n < N) ? S[(size_t)k * N + n] : 0.f;
    }
    __syncthreads();
#pragma unroll
    for (int r = 0; r < 4; r++) {
        const int n = n0 + ty + r * 8, k = k0 + tx;
        if (n < Npad && k < K) D[(size_t)n * K + k] = f2bf(tile[tx * 33 + ty + r * 8]);
    }
}

__global__ __launch_bounds__(256)
void prep_weights(const float* __restrict__ Wobj, ushort_t* __restrict__ WobjT,
                  const float* __restrict__ Wact, ushort_t* __restrict__ WactT,
                  const float* __restrict__ fc1W, ushort_t* __restrict__ fc1T,
                  const float* __restrict__ clfW, ushort_t* __restrict__ clfT,
                  const float* __restrict__ gc1W, ushort_t* __restrict__ W1t,
                  const float* __restrict__ gc3W, ushort_t* __restrict__ W3t,
                  const float* __restrict__ gc2W, ushort_t* __restrict__ W2bf,
                  const float* __restrict__ gc4W, ushort_t* __restrict__ W4bf)
{
    __shared__ float tile[32 * 33];
    const int b = blockIdx.x;
    const int t = threadIdx.x;
    const int tx = t & 31, ty = t >> 5;

    if (b < 1568) {
        const float* S; ushort_t* D; int K, N, Npad, nt, l;
        if      (b < 256)  { S = Wobj; D = WobjT; K = 512;  N = 512;  Npad = 512;  nt = 16; l = b; }
        else if (b < 512)  { S = Wact; D = WactT; K = 512;  N = 512;  Npad = 512;  nt = 16; l = b - 256; }
        else if (b < 1024) { S = fc1W; D = fc1T;  K = 512;  N = 1024; Npad = 1024; nt = 32; l = b - 512; }
        else if (b < 1536) { S = clfW; D = clfT;  K = 1024; N = 500;  Npad = 512;  nt = 16; l = b - 1024; }
        else if (b < 1552) { S = gc1W; D = W1t;   K = 512;  N = 32;   Npad = 32;   nt = 1;  l = b - 1536; }
        else               { S = gc3W; D = W3t;   K = 512;  N = 32;   Npad = 32;   nt = 1;  l = b - 1552; }
        tr_tile(S, D, K, N, Npad, l % nt, l / nt, tx, ty, tile);
    } else {
        const float* S = (b < 1576) ? gc2W : gc4W;
        ushort_t* D    = (b < 1576) ? W2bf : W4bf;
        const int i = (b < 1576 ? b - 1568 : b - 1576) * 256 + t;
        const float4 x = ((const float4*)S)[2 * i];
        const float4 y = ((const float4*)S)[2 * i + 1];
        unsigned r[4] = { pk2bf(x.x, x.y), pk2bf(x.z, x.w), pk2bf(y.x, y.y), pk2bf(y.z, y.w) };
        ((uint4*)D)[i] = *(uint4*)r;
    }
}

// ---------- MFMA GEMM core with global_load_lds staging ----------
// A: [M,K] fp32 or bf16. Bt: bf16 [N,K]. Tile 128x128, BK=32, 4 waves.
// LDS unpadded; bank conflicts broken by XOR-swizzling WHICH granule each lane
// fetches (global side), matched at the frag-read: A-fp32 g^=(row&7) (16way->2way),
// bf16 kc^=((row>>1)&3) (8way->2way). skip8: suppress stores to rows m%16==8.
__device__ __forceinline__ void store_out(ushort_t* C, size_t idx, float v) { C[idx] = f2bf(v); }
__device__ __forceinline__ void store_out(float* C, size_t idx, float v)    { C[idx] = v; }

template<int RELU, typename AT, typename OT>
__device__ __forceinline__ void gemm_core(
    const AT* __restrict__ A, const ushort_t* __restrict__ Bt,
    const float* __restrict__ bias, OT* __restrict__ C,
    int N, int K, int Nb, int row_mul, int row_add, int bm, int bn, int skip8,
    char* AsRaw, ushort_t* Bs)
{
    const int t = threadIdx.x;
    const int lane = t & 63, w = t >> 6;
    const int mb = (w & 1) * 64, nb = (w >> 1) * 64;
    const int fr = lane & 15, fq = lane >> 4;

    f32x4 acc[16];
#pragma unroll
    for (int i = 0; i < 16; i++) acc[i] = (f32x4){0.f, 0.f, 0.f, 0.f};

    const int brow = lane >> 2, bk = lane & 3;
    const int klog = bk ^ ((brow >> 1) & 3);       // bf16 staging swizzle
    const int arow = lane >> 3, ag = lane & 7;      // fp32 staging view

    for (int k0 = 0; k0 < K; k0 += 32) {
        __syncthreads();
        if constexpr (sizeof(AT) == 4) {
#pragma unroll
            for (int i = 0; i < 4; i++) {
                const int grp = w * 4 + i;
                const int row = grp * 8 + arow;
                const int gl = ag ^ (row & 7);
                dma16((const float*)A + (size_t)(bm + row) * K + k0 + gl * 4,
                      AsRaw + grp * 1024);
            }
        } else {
#pragma unroll
            for (int i = 0; i < 2; i++) {
                const int grp = w * 2 + i;
                const int row = grp * 16 + brow;
                dma16((const ushort_t*)A + (size_t)(bm + row) * K + k0 + klog * 8,
                      (ushort_t*)AsRaw + grp * 512);
            }
        }
#pragma unroll
        for (int i = 0; i < 2; i++) {
            const int grp = w * 2 + i;
            const int row = grp * 16 + brow;
            dma16(Bt + (size_t)(bn + row) * K + k0 + klog * 8, Bs + grp * 512);
        }
        __syncthreads();   // compiler emits s_waitcnt vmcnt(0) before s_barrier

        short8 af[4], bf[4];
        if constexpr (sizeof(AT) == 4) {
#pragma unroll
            for (int i = 0; i < 4; i++) {
                const int row = mb + i * 16 + fr;
                const float* base = (const float*)AsRaw + row * 32;
                const f32x4 p0 = *(const f32x4*)(base + (((2 * fq)     ^ (fr & 7)) * 4));
                const f32x4 p1 = *(const f32x4*)(base + (((2 * fq + 1) ^ (fr & 7)) * 4));
                unsigned rr[4] = { pk2bf(p0.x, p0.y), pk2bf(p0.z, p0.w),
                                   pk2bf(p1.x, p1.y), pk2bf(p1.z, p1.w) };
                af[i] = *(short8*)rr;
            }
        } else {
#pragma unroll
            for (int i = 0; i < 4; i++) {
                const int row = mb + i * 16 + fr;
                af[i] = *(const short8*)((const ushort_t*)AsRaw + row * 32 + (fq ^ ((fr >> 1) & 3)) * 8);
            }
        }
#pragma unroll
        for (int j = 0; j < 4; j++) {
            const int row = nb + j * 16 + fr;
            bf[j] = *(const short8*)(Bs + row * 32 + (fq ^ ((fr >> 1) & 3)) * 8);
        }
#pragma unroll
        for (int i = 0; i < 4; i++)
#pragma unroll
            for (int j = 0; j < 4; j++)
                acc[i * 4 + j] = __builtin_amdgcn_mfma_f32_16x16x32_bf16(
                    af[i], bf[j], acc[i * 4 + j], 0, 0, 0);
    }

#pragma unroll
    for (int j = 0; j < 4; j++) {
        const int n = bn + nb + j * 16 + fr;
        const float bv = (n < Nb) ? bias[n] : 0.f;
#pragma unroll
        for (int i = 0; i < 4; i++) {
            const f32x4 a = acc[i * 4 + j];
#pragma unroll
            for (int r = 0; r < 4; r++) {
                if (skip8 && (fq * 4 + r) == 8) continue;   // rows m%16==8 owned by act
                const int m = bm + mb + i * 16 + fq * 4 + r;
                float v = a[r] + bv;
                if (RELU) v = fmaxf(v, 0.f);
                store_out(C, ((size_t)m * row_mul + row_add) * (size_t)N + n, v);
            }
        }
    }
}

// obj (grid y 0..255) + act (grid y 256..271) fused in one dispatch.
// obj blocks skip rows m%16==8 (written by act blocks -> no intra-dispatch race).
__global__ __launch_bounds__(256)
void gemm_objact(const float* __restrict__ Ao, const ushort_t* __restrict__ Bo,
                 const float* __restrict__ bo,
                 const float* __restrict__ Aa, const ushort_t* __restrict__ Ba,
                 const float* __restrict__ ba, ushort_t* __restrict__ C)
{
    __shared__ __align__(16) char     AsRaw[128 * 32 * 4];
    __shared__ __align__(16) ushort_t Bs[128 * 32];
    if (blockIdx.y < 256)
        gemm_core<1, float, ushort_t>(Ao, Bo, bo, C, 512, 512, 512, 1, 0,
                                      blockIdx.y * 128, blockIdx.x * 128, 1, AsRaw, Bs);
    else
        gemm_core<1, float, ushort_t>(Aa, Ba, ba, C, 512, 512, 512, 16, 8,
                                      (blockIdx.y - 256) * 128, blockIdx.x * 128, 0, AsRaw, Bs);
}

template<int RELU, typename AT, typename OT>
__global__ __launch_bounds__(256)
void gemm_dma(const AT* __restrict__ A, const ushort_t* __restrict__ Bt,
              const float* __restrict__ bias, OT* __restrict__ C,
              int N, int K, int Nb, int row_mul, int row_add)
{
    __shared__ __align__(16) char     AsRaw[128 * 32 * sizeof(AT)];
    __shared__ __align__(16) ushort_t Bs[128 * 32];
    gemm_core<RELU, AT, OT>(A, Bt, bias, C, N, K, Nb, row_mul, row_add,
                            blockIdx.y * 128, blockIdx.x * 128, 0, AsRaw, Bs);
}

// ---------- graph stage: one wave per graph (unchanged from round 5) ----------
__global__ __launch_bounds__(64)
void graph_mfma(const ushort_t* __restrict__ obj,
                const ushort_t* __restrict__ W1t, const float* __restrict__ b1,
                const ushort_t* __restrict__ W2b, const float* __restrict__ b2,
                const ushort_t* __restrict__ W3t, const float* __restrict__ b3,
                const ushort_t* __restrict__ W4b, const float* __restrict__ b4,
                ushort_t* __restrict__ cbuf)
{
    __shared__ float ssb[16 * 17];
    __shared__ float adjt[16 * 20];
    __shared__ float t1s[16 * 36];
    __shared__ float t3s[16 * 36];
    __shared__ float x1s[16 * 36];
    __shared__ float y2s[16 * 36];
    __shared__ float y22s[16 * 17];
    __shared__ float a3t[16 * 20];
    __shared__ float dv[16], dv3[16], nrm[16], cA[16], cA3[16];
    __shared__ float zc1[32], zc4[32];

    const int lane = threadIdx.x;
    const int r = lane & 15, fq = lane >> 4;
    const ushort_t* xg = obj + (size_t)blockIdx.x * 8192;

    short8 xf[16];
#pragma unroll
    for (int kk = 0; kk < 16; kk++)
        xf[kk] = *(const short8*)(xg + r * 512 + kk * 32 + fq * 8);

    f32x4 sacc = (f32x4){0.f, 0.f, 0.f, 0.f};
#pragma unroll
    for (int kk = 0; kk < 16; kk++)
        sacc = __builtin_amdgcn_mfma_f32_16x16x32_bf16(xf[kk], xf[kk], sacc, 0, 0, 0);

    f32x4 a10 = (f32x4){0.f,0.f,0.f,0.f}, a11 = a10, a30 = a10, a31 = a10;
#pragma unroll
    for (int kk = 0; kk < 16; kk++) {
        const short8 w10 = *(const short8*)(W1t + (size_t)(r)      * 512 + kk * 32 + fq * 8);
        const short8 w11 = *(const short8*)(W1t + (size_t)(16 + r) * 512 + kk * 32 + fq * 8);
        const short8 w30 = *(const short8*)(W3t + (size_t)(r)      * 512 + kk * 32 + fq * 8);
        const short8 w31 = *(const short8*)(W3t + (size_t)(16 + r) * 512 + kk * 32 + fq * 8);
        a10 = __builtin_amdgcn_mfma_f32_16x16x32_bf16(xf[kk], w10, a10, 0, 0, 0);
        a11 = __builtin_amdgcn_mfma_f32_16x16x32_bf16(xf[kk], w11, a11, 0, 0, 0);
        a30 = __builtin_amdgcn_mfma_f32_16x16x32_bf16(xf[kk], w30, a30, 0, 0, 0);
        a31 = __builtin_amdgcn_mfma_f32_16x16x32_bf16(xf[kk], w31, a31, 0, 0, 0);
    }

#pragma unroll
    for (int i = 0; i < 4; i++) {
        const int m = fq * 4 + i;
        ssb[m * 17 + r] = sacc[i];
        t1s[m * 36 + r]      = a10[i];
        t1s[m * 36 + 16 + r] = a11[i];
        t3s[m * 36 + r]      = a30[i];
        t3s[m * 36 + 16 + r] = a31[i];
    }
    __syncthreads();

    if (lane < 16) {
        float m = ssb[lane * 17];
#pragma unroll
        for (int j = 1; j < 16; j++) m = fmaxf(m, ssb[lane * 17 + j]);
        float s = 0.f;
#pragma unroll
        for (int j = 0; j < 16; j++) {
            const float e = expf(ssb[lane * 17 + j] - m);
            ssb[lane * 17 + j] = e; s += e;
        }
        dv[lane] = rsqrtf(s);
    }
    __syncthreads();

    {
        const float di = dv[r];
#pragma unroll
        for (int p = 0; p < 4; p++) {
            const int j = fq * 4 + p;
            adjt[j * 20 + r] = ssb[r * 17 + j] * di * dv[j];
        }
    }
    __syncthreads();

    if (lane < 16) {
        float s = 0.f;
#pragma unroll
        for (int i = 0; i < 16; i++) s += adjt[lane * 20 + i];
        cA[lane] = s;
    }

    {
        const int c = lane & 31, hi = lane >> 5;
        const float bb1 = b1[c], bb3 = b3[c];
        float ax[8], ay[8];
#pragma unroll
        for (int i = 0; i < 8; i++) { ax[i] = bb1; ay[i] = bb3; }
#pragma unroll
        for (int j = 0; j < 16; j++) {
            const float t1v = t1s[j * 36 + c], t3v = t3s[j * 36 + c];
            const float4 p = *(const float4*)&adjt[j * 20 + hi * 8];
            const float4 q = *(const float4*)&adjt[j * 20 + hi * 8 + 4];
            ax[0] = fmaf(p.x, t1v, ax[0]); ax[1] = fmaf(p.y, t1v, ax[1]);
            ax[2] = fmaf(p.z, t1v, ax[2]); ax[3] = fmaf(p.w, t1v, ax[3]);
            ax[4] = fmaf(q.x, t1v, ax[4]); ax[5] = fmaf(q.y, t1v, ax[5]);
            ax[6] = fmaf(q.z, t1v, ax[6]); ax[7] = fmaf(q.w, t1v, ax[7]);
            ay[0] = fmaf(p.x, t3v, ay[0]); ay[1] = fmaf(p.y, t3v, ay[1]);
            ay[2] = fmaf(p.z, t3v, ay[2]); ay[3] = fmaf(p.w, t3v, ay[3]);
            ay[4] = fmaf(q.x, t3v, ay[4]); ay[5] = fmaf(q.y, t3v, ay[5]);
            ay[6] = fmaf(q.z, t3v, ay[6]); ay[7] = fmaf(q.w, t3v, ay[7]);
        }
#pragma unroll
        for (int i = 0; i < 8; i++) {
            x1s[(hi * 8 + i) * 36 + c] = fmaxf(ax[i], 0.f);
            y2s[(hi * 8 + i) * 36 + c] = fmaxf(ay[i], 0.f);
        }
    }
    __syncthreads();

    {
        const int i2 = lane >> 2, j0 = (lane & 3) * 4;
        float a4[4] = {0.f, 0.f, 0.f, 0.f};
#pragma unroll
        for (int k4 = 0; k4 < 8; k4++) {
            const float4 yi = *(const float4*)&y2s[i2 * 36 + k4 * 4];
#pragma unroll
            for (int p = 0; p < 4; p++) {
                const float4 yj = *(const float4*)&y2s[(j0 + p) * 36 + k4 * 4];
                a4[p] = fmaf(yi.x, yj.x, a4[p]); a4[p] = fmaf(yi.y, yj.y, a4[p]);
                a4[p] = fmaf(yi.z, yj.z, a4[p]); a4[p] = fmaf(yi.w, yj.w, a4[p]);
            }
        }
#pragma unroll
        for (int p = 0; p < 4; p++) y22s[i2 * 17 + j0 + p] = a4[p];
    }
    __syncthreads();

    if (lane < 16) {
        float sq = 0.f;
#pragma unroll
        for (int j = 0; j < 16; j++) { const float v = y22s[lane * 17 + j]; sq = fmaf(v, v, sq); }
        nrm[lane] = sqrtf(sq);
    }
    __syncthreads();

    {
        const float ni = nrm[r];
#pragma unroll
        for (int p = 0; p < 4; p++) {
            const int j = fq * 4 + p;
            a3t[j * 20 + r] = 1.0f + y22s[r * 17 + j] / (ni * nrm[j]);
        }
    }
    __syncthreads();

    if (lane < 16) {
        float s = 0.f;
#pragma unroll
        for (int j = 0; j < 16; j++) s += a3t[j * 20 + lane];
        dv3[lane] = rsqrtf(s);
    }
    __syncthreads();

    if (lane < 16) {
        float s = 0.f;
#pragma unroll
        for (int i = 0; i < 16; i++) s = fmaf(a3t[lane * 20 + i], dv3[i], s);
        cA3[lane] = s * dv3[lane];
    }
    __syncthreads();

    if (lane < 32) {
        float s1 = 0.f, s4 = 0.f;
#pragma unroll
        for (int j = 0; j < 16; j++) {
            s1 = fmaf(cA[j],  x1s[j * 36 + lane], s1);
            s4 = fmaf(cA3[j], y2s[j * 36 + lane], s4);
        }
        zc1[lane] = s1; zc4[lane] = s4;
    }
    __syncthreads();

    {
        float om[8] = {0,0,0,0,0,0,0,0};
#pragma unroll
        for (int m = 0; m < 16; m++) {
            const uint4 q = *(const uint4*)(xg + m * 512 + lane * 8);
            om[0] += bflo(q.x); om[1] += bfhi(q.x);
            om[2] += bflo(q.y); om[3] += bfhi(q.y);
            om[4] += bflo(q.z); om[5] += bfhi(q.z);
            om[6] += bflo(q.w); om[7] += bfhi(q.w);
        }
        float gm[8] = {0,0,0,0,0,0,0,0};
        for (int k = 0; k < 32; k++) {
            const float z1 = zc1[k], z4 = zc4[k];
            const uint4 w2 = *(const uint4*)(W2b + (size_t)k * 512 + lane * 8);
            const uint4 w4 = *(const uint4*)(W4b + (size_t)k * 512 + lane * 8);
            gm[0] = fmaf(z1, bflo(w2.x), gm[0]); gm[0] = fmaf(z4, bflo(w4.x), gm[0]);
            gm[1] = fmaf(z1, bfhi(w2.x), gm[1]); gm[1] = fmaf(z4, bfhi(w4.x), gm[1]);
            gm[2] = fmaf(z1, bflo(w2.y), gm[2]); gm[2] = fmaf(z4, bflo(w4.y), gm[2]);
            gm[3] = fmaf(z1, bfhi(w2.y), gm[3]); gm[3] = fmaf(z4, bfhi(w4.y), gm[3]);
            gm[4] = fmaf(z1, bflo(w2.z), gm[4]); gm[4] = fmaf(z4, bflo(w4.z), gm[4]);
            gm[5] = fmaf(z1, bfhi(w2.z), gm[5]); gm[5] = fmaf(z4, bfhi(w4.z), gm[5]);
            gm[6] = fmaf(z1, bflo(w2.w), gm[6]); gm[6] = fmaf(z4, bflo(w4.w), gm[6]);
            gm[7] = fmaf(z1, bfhi(w2.w), gm[7]); gm[7] = fmaf(z4, bfhi(w4.w), gm[7]);
        }
        const float4 b2a = *(const float4*)&b2[lane * 8];
        const float4 b2b = *(const float4*)&b2[lane * 8 + 4];
        const float4 b4a = *(const float4*)&b4[lane * 8];
        const float4 b4b = *(const float4*)&b4[lane * 8 + 4];
        const float bs[8] = { b2a.x + b4a.x, b2a.y + b4a.y, b2a.z + b4a.z, b2a.w + b4a.w,
                              b2b.x + b4b.x, b2b.y + b4b.y, b2b.z + b4b.z, b2b.w + b4b.w };
        ushort_t pk[8];
#pragma unroll
        for (int c = 0; c < 8; c++) {
            const float gmean = 0.5f * bs[c] + gm[c] * (1.0f / 32.0f);
            const float feat  = 0.5f * (om[c] * 0.0625f + gmean);
            pk[c] = f2bf(fmaxf(feat, 0.f));
        }
        *(uint4*)(cbuf + (size_t)blockIdx.x * 512 + lane * 8) = *(uint4*)pk;
    }
}

// ---------- cmean[32,1024] = mean over T=64 of c2[2048,1024] ----------
__global__ __launch_bounds__(256)
void mean_c2(const ushort_t* __restrict__ c2, float* __restrict__ cmean)
{
    const int idx = blockIdx.x * 256 + threadIdx.x;
    const int n = idx >> 10, k = idx & 1023;
    const ushort_t* p = c2 + (size_t)n * 64 * 1024 + k;
    float s = 0.f;
#pragma unroll 8
    for (int tt = 0; tt < 64; tt++) {
        union { unsigned u; float f; } x; x.u = ((unsigned)p[tt * 1024]) << 16;
        s += x.f;
    }
    cmean[idx] = s * (1.0f / 64.0f);
}

// ---------- tiny clf (mean-before-affine) ----------
__global__ __launch_bounds__(256)
void clf_small(const float* __restrict__ cmean, const ushort_t* __restrict__ clfT,
               const float* __restrict__ clf_b, float* __restrict__ out)
{
    const int t = threadIdx.x;
    const int n = t & 31, jo = t >> 5;
    const int j = blockIdx.x * 8 + jo;
    const float4* cm = (const float4*)(cmean + (size_t)n * 1024);
    const uint2*  wr = (const uint2*)(clfT + (size_t)(j < 500 ? j : 499) * 1024);
    float acc = 0.f;
#pragma unroll 4
    for (int k4 = 0; k4 < 256; k4++) {
        const float4 c = cm[k4];
        const uint2  w = wr[k4];
        acc = fmaf(c.x, bflo(w.x), acc);
        acc = fmaf(c.y, bfhi(w.x), acc);
        acc = fmaf(c.z, bflo(w.y), acc);
        acc = fmaf(c.w, bfhi(w.y), acc);
    }
    if (j < 500) out[(size_t)n * 500 + j] = acc + clf_b[j];
}

// ---------- launcher ----------
extern "C" void kernel_launch(void* const* d_in, const int* in_sizes, int n_in,
                              void* d_out, int out_size, void* d_ws, size_t ws_size,
                              hipStream_t stream)
{
    const float* object_raw = (const float*)d_in[0];
    const float* action_raw = (const float*)d_in[1];
    const float* W_obj = (const float*)d_in[2];
    const float* b_obj = (const float*)d_in[3];
    const float* W_act = (const float*)d_in[4];
    const float* b_act = (const float*)d_in[5];
    const float* gc1_W = (const float*)d_in[6];
    const float* gc1_b = (const float*)d_in[7];
    const float* gc2_W = (const float*)d_in[8];
    const float* gc2_b = (const float*)d_in[9];
    const float* gc3_W = (const float*)d_in[10];
    const float* gc3_b = (const float*)d_in[11];
    const float* gc4_W = (const float*)d_in[12];
    const float* gc4_b = (const float*)d_in[13];
    const float* fc1_W = (const float*)d_in[14];
    const float* fc1_b = (const float*)d_in[15];
    const float* clf_W = (const float*)d_in[16];
    const float* clf_b = (const float*)d_in[17];

    char* ws = (char*)d_ws;
    const size_t MB = 1024 * 1024;
    ushort_t* obj_bf = (ushort_t*)(ws);                       // 32 MB
    ushort_t* cbuf   = (ushort_t*)(ws + 32 * MB);             // 2 MB
    ushort_t* c2     = (ushort_t*)(ws + 34 * MB);             // 4 MB
    float*    cmean  = (float*)   (ws + 38 * MB);             // 128 KB
    ushort_t* WobjT  = (ushort_t*)(ws + 39 * MB);             // 512 KB
    ushort_t* WactT  = (ushort_t*)(ws + 39 * MB + 512 * 1024);
    ushort_t* fc1T   = (ushort_t*)(ws + 40 * MB);             // 1 MB
    ushort_t* clfT   = (ushort_t*)(ws + 41 * MB);             // 1 MB
    ushort_t* W1t    = (ushort_t*)(ws + 42 * MB);
    ushort_t* W3t    = (ushort_t*)(ws + 42 * MB + 32 * 1024);
    ushort_t* W2bf   = (ushort_t*)(ws + 42 * MB + 64 * 1024);
    ushort_t* W4bf   = (ushort_t*)(ws + 42 * MB + 96 * 1024);

    // 1. all weight preps in one dispatch
    prep_weights<<<dim3(1584), 256, 0, stream>>>(
        W_obj, WobjT, W_act, WactT, fc1_W, fc1T, clf_W, clfT,
        gc1_W, W1t, gc3_W, W3t, gc2_W, W2bf, gc4_W, W4bf);

    // 2. obj + act GEMMs fused (obj skips rows m%16==8; act writes them)
    gemm_objact<<<dim3(4, 272), 256, 0, stream>>>(
        object_raw, WobjT, b_obj, action_raw, WactT, b_act, obj_bf);

    // 3. graph stage: one wave per graph
    graph_mfma<<<dim3(2048), 64, 0, stream>>>(
        obj_bf, W1t, gc1_b, W2bf, gc2_b, W3t, gc3_b, W4bf, gc4_b, cbuf);

    // 4. c2 = relu(cbuf @ fc1_W + fc1_b)
    gemm_dma<1, ushort_t, ushort_t><<<dim3(8, 16), 256, 0, stream>>>(
        cbuf, fc1T, fc1_b, c2, 1024, 512, 1024, 1, 0);

    // 5. cmean = mean over T
    mean_c2<<<dim3(128), 256, 0, stream>>>(c2, cmean);

    // 6. out = cmean @ clf_W + clf_b
    clf_small<<<dim3(63), 256, 0, stream>>>(cmean, clfT, clf_b, (float*)d_out);
}